// Round 5
// baseline (473.330 us; speedup 1.0000x reference)
//
#include <hip/hip_runtime.h>
#include <math.h>

// Problem constants
#define NB    64            // batch
#define LSEQ  196           // H*W = 14*14
#define HID   768
#define NHEAD 24
#define HDIM  32
#define FFN   3072
#define ROWS  (NB * LSEQ)   // 12544
#define RATE  0.2f
#define LN_EPS 1e-5f

typedef unsigned short bf16_t;                              // raw bf16 bits
typedef short s16x8 __attribute__((ext_vector_type(8)));    // 8 bf16 (4 VGPRs)
typedef float f32x4 __attribute__((ext_vector_type(4)));    // MFMA accumulator

// fp32 -> bf16 round-to-nearest-even (bit pattern in ushort)
__device__ __forceinline__ unsigned short f2bf(float f) {
    unsigned u = __float_as_uint(f);
    unsigned r = u + 0x7fffu + ((u >> 16) & 1u);
    return (unsigned short)(r >> 16);
}

// async global->LDS, 16 B per lane, dest = wave-uniform base + lane*16
#define GLOAD_LDS16(g, l)                                                  \
    __builtin_amdgcn_global_load_lds(                                      \
        (const __attribute__((address_space(1))) void*)(g),                \
        (__attribute__((address_space(3))) void*)(l), 16, 0, 0)

// ---------------------------------------------------------------------------
// fp32 -> bf16 convert for all three weight matrices in one launch.
// ---------------------------------------------------------------------------
#define WOUT4 (HID * HID / 4)
#define W14   (FFN * HID / 4)
__global__ __launch_bounds__(256) void cvt_w_kernel(
    const float* __restrict__ w_out, const float* __restrict__ w1,
    const float* __restrict__ w2, bf16_t* __restrict__ wob,
    bf16_t* __restrict__ w1b, bf16_t* __restrict__ w2b)
{
    int i = blockIdx.x * 256 + threadIdx.x;
    const float* src; bf16_t* dst; int off;
    if (i < WOUT4)            { src = w_out; dst = wob; off = i; }
    else if (i < WOUT4 + W14) { src = w1;    dst = w1b; off = i - WOUT4; }
    else                      { src = w2;    dst = w2b; off = i - WOUT4 - W14; }
    float4 v = ((const float4*)src)[off];
    uint2 p;
    p.x = (unsigned)f2bf(v.x) | ((unsigned)f2bf(v.y) << 16);
    p.y = (unsigned)f2bf(v.z) | ((unsigned)f2bf(v.w) << 16);
    ((uint2*)dst)[off] = p;
}

// ---------------------------------------------------------------------------
// LayerNorm over last dim (768). One block (256 threads) per row. bf16 out.
// ---------------------------------------------------------------------------
__global__ __launch_bounds__(256) void ln_kernel(
    const float* __restrict__ x, const float* __restrict__ g,
    const float* __restrict__ b, bf16_t* __restrict__ yv)
{
    int row = blockIdx.x;
    int tid = threadIdx.x;  // 0..255
    const float* xr = x + (size_t)row * HID;
    float v0 = xr[tid], v1 = xr[tid + 256], v2 = xr[tid + 512];
    __shared__ float rs[256], rs2[256];
    rs[tid]  = v0 + v1 + v2;
    rs2[tid] = v0 * v0 + v1 * v1 + v2 * v2;
    __syncthreads();
    for (int off = 128; off > 0; off >>= 1) {
        if (tid < off) { rs[tid] += rs[tid + off]; rs2[tid] += rs2[tid + off]; }
        __syncthreads();
    }
    float mean = rs[0] * (1.0f / HID);
    float var  = rs2[0] * (1.0f / HID) - mean * mean;
    float rstd = rsqrtf(var + LN_EPS);
    bf16_t* yr = yv + (size_t)row * HID;
    yr[tid]       = f2bf((v0 - mean) * rstd * g[tid]       + b[tid]);
    yr[tid + 256] = f2bf((v1 - mean) * rstd * g[tid + 256] + b[tid + 256]);
    yr[tid + 512] = f2bf((v2 - mean) * rstd * g[tid + 512] + b[tid + 512]);
}

// ---------------------------------------------------------------------------
// Fused LN1 + QKV via MFMA. One block (256 thr = 4 waves) per 16 tokens.
// ---------------------------------------------------------------------------
#define QKV_T 16   // tokens per block
__global__ __launch_bounds__(256) void ln_qkv_mfma_kernel(
    const float* __restrict__ x, const float* __restrict__ g,
    const float* __restrict__ b,
    const float* __restrict__ wq, const float* __restrict__ wk,
    const float* __restrict__ wv,
    bf16_t* __restrict__ q, bf16_t* __restrict__ k, bf16_t* __restrict__ v)
{
    int tid = threadIdx.x;
    int w = tid >> 6, lane = tid & 63;
    int lr = lane & 15, lq = lane >> 4;

    __shared__ __align__(16) bf16_t Xs[QKV_T * 24 * 32];   // 24576 B
    __shared__ __align__(16) bf16_t Wqs[32 * 32];          //  2048 B x3
    __shared__ __align__(16) bf16_t Wks[32 * 32];
    __shared__ __align__(16) bf16_t Wvs[32 * 32];

    for (int i = tid; i < 1024; i += 256) {
        Wqs[i] = f2bf(wq[i]);
        Wks[i] = f2bf(wk[i]);
        Wvs[i] = f2bf(wv[i]);
    }

    float4 gv[3], bv[3];
#pragma unroll
    for (int i = 0; i < 3; i++) {
        gv[i] = ((const float4*)g)[lane + i * 64];
        bv[i] = ((const float4*)b)[lane + i * 64];
    }

    for (int j = 0; j < 4; j++) {
        int lt = w * 4 + j;
        size_t row = (size_t)blockIdx.x * QKV_T + lt;
        const float4* xr = (const float4*)(x + row * HID);
        float4 xv[3];
        float s = 0.f, s2 = 0.f;
#pragma unroll
        for (int i = 0; i < 3; i++) {
            xv[i] = xr[lane + i * 64];
            s  += xv[i].x + xv[i].y + xv[i].z + xv[i].w;
            s2 += xv[i].x * xv[i].x + xv[i].y * xv[i].y
                + xv[i].z * xv[i].z + xv[i].w * xv[i].w;
        }
#pragma unroll
        for (int d = 1; d < 64; d <<= 1) {
            s  += __shfl_xor(s, d);
            s2 += __shfl_xor(s2, d);
        }
        float mean = s * (1.0f / HID);
        float rstd = rsqrtf(s2 * (1.0f / HID) - mean * mean + LN_EPS);
#pragma unroll
        for (int i = 0; i < 3; i++) {
            int idx  = (lane + i * 64) * 4;
            int head = idx >> 5, d0 = idx & 31;
            float o0 = (xv[i].x - mean) * rstd * gv[i].x + bv[i].x;
            float o1 = (xv[i].y - mean) * rstd * gv[i].y + bv[i].y;
            float o2 = (xv[i].z - mean) * rstd * gv[i].z + bv[i].z;
            float o3 = (xv[i].w - mean) * rstd * gv[i].w + bv[i].w;
            uint2 p;
            p.x = (unsigned)f2bf(o0) | ((unsigned)f2bf(o1) << 16);
            p.y = (unsigned)f2bf(o2) | ((unsigned)f2bf(o3) << 16);
            *(uint2*)&Xs[(lt * 24 + head) * 32 + d0] = p;
        }
    }
    __syncthreads();

    s16x8 bq[2], bk[2], bvv[2];
    bq[0]  = *(const s16x8*)&Wqs[lr * 32 + lq * 8];
    bq[1]  = *(const s16x8*)&Wqs[(16 + lr) * 32 + lq * 8];
    bk[0]  = *(const s16x8*)&Wks[lr * 32 + lq * 8];
    bk[1]  = *(const s16x8*)&Wks[(16 + lr) * 32 + lq * 8];
    bvv[0] = *(const s16x8*)&Wvs[lr * 32 + lq * 8];
    bvv[1] = *(const s16x8*)&Wvs[(16 + lr) * 32 + lq * 8];

    for (int t = 0; t < 6; t++) {
        int tile = w * 6 + t;
        s16x8 aX = *(const s16x8*)&Xs[(tile * 16 + lr) * 32 + lq * 8];
        f32x4 z = {};
        f32x4 aq0 = __builtin_amdgcn_mfma_f32_16x16x32_bf16(aX, bq[0],  z, 0, 0, 0);
        f32x4 aq1 = __builtin_amdgcn_mfma_f32_16x16x32_bf16(aX, bq[1],  z, 0, 0, 0);
        f32x4 ak0 = __builtin_amdgcn_mfma_f32_16x16x32_bf16(aX, bk[0],  z, 0, 0, 0);
        f32x4 ak1 = __builtin_amdgcn_mfma_f32_16x16x32_bf16(aX, bk[1],  z, 0, 0, 0);
        f32x4 av0 = __builtin_amdgcn_mfma_f32_16x16x32_bf16(aX, bvv[0], z, 0, 0, 0);
        f32x4 av1 = __builtin_amdgcn_mfma_f32_16x16x32_bf16(aX, bvv[1], z, 0, 0, 0);
        int rbase = tile * 16 + lq * 4;
#pragma unroll
        for (int r = 0; r < 4; r++) {
            int xrow = rbase + r;
            int t_loc = xrow / 24, head = xrow - t_loc * 24;
            size_t gb = ((size_t)blockIdx.x * QKV_T + t_loc) * HID + head * 32;
            q[gb + lr]      = f2bf(aq0[r]);
            q[gb + 16 + lr] = f2bf(aq1[r]);
            k[gb + lr]      = f2bf(ak0[r]);
            k[gb + 16 + lr] = f2bf(ak1[r]);
            v[gb + lr]      = f2bf(av0[r]);
            v[gb + 16 + lr] = f2bf(av1[r]);
        }
    }
}

// ---------------------------------------------------------------------------
// MFMA attention: one block (256 thr = 4 waves) per (h, n). Unchanged.
// ---------------------------------------------------------------------------
#define VT_S 232   // V^T row stride (bf16)
#define P_S  40    // P row stride (bf16)

__global__ __launch_bounds__(256) void attn_mfma_kernel(
    const bf16_t* __restrict__ q, const bf16_t* __restrict__ k,
    const bf16_t* __restrict__ v, const float* __restrict__ rel_bias,
    bf16_t* __restrict__ o)
{
    int h = blockIdx.x;   // 0..23
    int n = blockIdx.y;   // 0..63
    int tid = threadIdx.x;
    int w = tid >> 6, lane = tid & 63;
    int lr = lane & 15;
    int lq = lane >> 4;

    __shared__ __align__(16) bf16_t Qs[208 * 32];
    __shared__ __align__(16) bf16_t Ks[224 * 32];
    __shared__ __align__(16) bf16_t Vt[32 * VT_S];
    __shared__ float bsh[28 * 28];
    __shared__ __align__(16) bf16_t Ps[4][16 * P_S];

    size_t base = (size_t)n * LSEQ * HID + (size_t)h * HDIM;

    for (int i = tid; i < 224 * 4; i += 256) {
        int r = i >> 2, c = i & 3;
        uint4 kv = make_uint4(0, 0, 0, 0);
        if (r < 196) kv = *(const uint4*)&k[base + (size_t)r * HID + c * 8];
        *(uint4*)&Ks[r * 32 + c * 8] = kv;
        if (r < 208) {
            uint4 qv = make_uint4(0, 0, 0, 0);
            if (r < 196) qv = *(const uint4*)&q[base + (size_t)r * HID + c * 8];
            *(uint4*)&Qs[r * 32 + c * 8] = qv;
        }
    }
    for (int i = tid; i < 196 * 16; i += 256) {
        int key = i >> 4, d2 = (i & 15) * 2;
        unsigned u = *(const unsigned*)&v[base + (size_t)key * HID + d2];
        Vt[d2 * VT_S + key]       = (bf16_t)(u & 0xffffu);
        Vt[(d2 + 1) * VT_S + key] = (bf16_t)(u >> 16);
    }
    for (int i = tid; i < 32 * 32; i += 256) {
        int d = i >> 5, kp = i & 31;
        if (kp < 28) Vt[d * VT_S + 196 + kp] = 0;
    }
    for (int i = tid; i < 784; i += 256) bsh[i] = rel_bias[i];
    __syncthreads();

    const float inv_sqrt_d = 0.17677669529663687f;
    bf16_t* P = Ps[w];

    for (int qt = w; qt < 13; qt += 4) {
        s16x8 aQ = *(const s16x8*)&Qs[(qt * 16 + lr) * 32 + lq * 8];

        int bb[4]; bool qvalid[4];
#pragma unroll
        for (int r = 0; r < 4; r++) {
            int qr = qt * 16 + lq * 4 + r;
            qvalid[r] = qr < LSEQ;
            int qq = qvalid[r] ? qr : 0;
            int qi = qq / 14, qj = qq - 14 * (qq / 14);
            bb[r] = (qi + 14) * 28 + (qj + 14);
        }

        f32x4 sf[14];
#pragma unroll
        for (int kt = 0; kt < 14; kt++) {
            s16x8 bK = *(const s16x8*)&Ks[(kt * 16 + lr) * 32 + lq * 8];
            f32x4 z = {};
            sf[kt] = __builtin_amdgcn_mfma_f32_16x16x32_bf16(aQ, bK, z, 0, 0, 0);
        }
#pragma unroll
        for (int kt = 0; kt < 14; kt++) {
            int key = kt * 16 + lr;
            bool kv = key < LSEQ;
            int kk2 = kv ? key : 0;
            int ip = kk2 / 14, jp = kk2 - 14 * ip;
            int boff = ip * 28 + jp;
#pragma unroll
            for (int r = 0; r < 4; r++) {
                float val = (sf[kt][r] + bsh[bb[r] - boff]) * inv_sqrt_d;
                sf[kt][r] = kv ? val : -1e30f;
            }
        }
        float mx[4];
#pragma unroll
        for (int r = 0; r < 4; r++) {
            float m = sf[0][r];
#pragma unroll
            for (int kt = 1; kt < 14; kt++) m = fmaxf(m, sf[kt][r]);
            mx[r] = m;
        }
#pragma unroll
        for (int d = 1; d < 16; d <<= 1)
#pragma unroll
            for (int r = 0; r < 4; r++)
                mx[r] = fmaxf(mx[r], __shfl_xor(mx[r], d));
        float sum[4] = {0.f, 0.f, 0.f, 0.f};
#pragma unroll
        for (int kt = 0; kt < 14; kt++)
#pragma unroll
            for (int r = 0; r < 4; r++) {
                float p = __expf(sf[kt][r] - mx[r]);
                sf[kt][r] = p;
                sum[r] += p;
            }
#pragma unroll
        for (int d = 1; d < 16; d <<= 1)
#pragma unroll
            for (int r = 0; r < 4; r++)
                sum[r] += __shfl_xor(sum[r], d);

        f32x4 oacc[2] = {};
#pragma unroll
        for (int kc = 0; kc < 7; kc++) {
#pragma unroll
            for (int r = 0; r < 4; r++) {
                P[(lq * 4 + r) * P_S + lr]      = f2bf(sf[2 * kc][r]);
                P[(lq * 4 + r) * P_S + 16 + lr] = f2bf(sf[2 * kc + 1][r]);
            }
            s16x8 aP = *(const s16x8*)&P[lr * P_S + lq * 8];
#pragma unroll
            for (int dt = 0; dt < 2; dt++) {
                s16x8 bV = *(const s16x8*)&Vt[(dt * 16 + lr) * VT_S + kc * 32 + lq * 8];
                oacc[dt] = __builtin_amdgcn_mfma_f32_16x16x32_bf16(aP, bV, oacc[dt], 0, 0, 0);
            }
        }
#pragma unroll
        for (int r = 0; r < 4; r++) {
            if (qvalid[r]) {
                float inv_l = 1.0f / sum[r];
                size_t ob = base + (size_t)(qt * 16 + lq * 4 + r) * HID;
                o[ob + lr]      = f2bf(oacc[0][r] * inv_l);
                o[ob + 16 + lr] = f2bf(oacc[1][r] * inv_l);
            }
        }
    }
}

// ---------------------------------------------------------------------------
// GELU helper
// ---------------------------------------------------------------------------
__device__ __forceinline__ float gelu_fast(float x) {
    // 0.5x(1+tanh(0.79788456(x+0.044715x^3))) = x - x/(e^{2z}+1)
    float z2 = 1.5957691216f * (x + 0.044715f * x * x * x);  // 2z
    return x - x * __frcp_rn(__expf(z2) + 1.0f);
}

// ---------------------------------------------------------------------------
// FFN1 kernel: 3-buf counted-vmcnt pipeline, BARRIER-MINIMAL (r5 change).
// BM=256 x BN=128, BK=64, 512 thr = 8 waves (4M x 2N, per-wave 64x64).
// Per K-tile: ds_reads kc0 + 3 stage loads + 16 MFMA, ds_reads kc1 +
// 3 stage loads + 16 MFMA, then ONE gate: vmcnt(6) + s_barrier.
// The r4 mid-phase barriers were not correctness-required (both phases read
// the same buffer); removing them lets the 2 waves/SIMD slip so one wave's
// MFMA covers the other's ds_reads.
//
// Race ledger (iter t; ct=t%3; staging target bs2=(t+2)%3=(t-1)%3):
//   * stage(t+2) writes buf[(t-1)%3]: every wave's iter t-1 ds_reads of that
//     buffer retired (implicit lgkmcnt before its MFMAs) before it reached
//     iter t-1's gate barrier; all waves passed that barrier before any
//     iter-t stage issues; gload LDS-writes occur after issue. Safe.
//   * compute(ct): tile t's 6 loads were >= 2 gates old: gate at iter t-1
//     guaranteed (vmcnt(6)) that tile t's loads landed, block-wide.
//   * gate end of iter t: per wave <=12 outstanding (t+1:6, t+2:6);
//     vmcnt(6) leaves only t+2's => t+1 landed; barrier makes block-wide.
//   * tail: t+2>=NT stages nothing; gate vmcnt(0). Last iter: no gate.
// ---------------------------------------------------------------------------
template <int MODE, bool OBF>
__global__ __launch_bounds__(512, 2) void gemm_fph(
    const bf16_t* __restrict__ A, const bf16_t* __restrict__ B,
    void* __restrict__ Cv, int M, int N, int K,
    const float* __restrict__ bias, const float* __restrict__ res, float scale)
{
    constexpr int BM = 256, BN = 128, BK = 64, NBUF = 3;
    __shared__ __align__(16) bf16_t As[NBUF][BM * BK];   // 3 x 32 KiB
    __shared__ __align__(16) bf16_t Bs[NBUF][BN * BK];   // 3 x 16 KiB

    int tid  = threadIdx.x;
    int w    = tid >> 6;          // 0..7
    int lane = tid & 63;

    int mb = M / BM, nb = N / BN;
    int gblk = blockIdx.x;
    int full = mb & ~7;
    int gfull = full * nb;
    int m_, n_;
    if (gblk < gfull) {
        int sg = gblk / (8 * nb), u = gblk - sg * (8 * nb);
        m_ = sg * 8 + (u & 7); n_ = u >> 3;
    } else {
        int u = gblk - gfull, rem = mb - full;
        m_ = full + u % rem; n_ = u / rem;
    }
    int bm = m_ * BM, bn = n_ * BN;

    int wm = (w >> 1) * 64;       // 4 M-waves
    int wn = (w & 1) * 64;        // 2 N-waves
    int lr = lane & 15;
    int lq = lane >> 4;

    int srowl = lane >> 3;                    // 0..7
    int scb   = ((lane & 7) ^ srowl) * 16;    // swizzled source byte offset
    const char* Ab = (const char*)A;
    const char* Bb = (const char*)B;

    f32x4 acc[4][4] = {};

    auto stageA = [&](int t, int bi, int j) {
        int rb = j * 64 + w * 8;
        GLOAD_LDS16(Ab + ((size_t)(bm + rb + srowl) * K + t * BK) * 2 + scb,
                    &As[bi][rb * BK]);
    };
    auto stageB = [&](int t, int bi, int j) {
        int rb = j * 64 + w * 8;
        GLOAD_LDS16(Bb + ((size_t)(bn + rb + srowl) * K + t * BK) * 2 + scb,
                    &Bs[bi][rb * BK]);
    };

    const int NT = K / BK;        // >= 3 (12 or 48)
    int sw = lr & 7;

    // prologue: tiles 0 and 1 fully staged; gate tile 0
    stageA(0, 0, 0); stageA(0, 0, 1); stageA(0, 0, 2); stageA(0, 0, 3);
    stageB(0, 0, 0); stageB(0, 0, 1);
    stageA(1, 1, 0); stageA(1, 1, 1); stageA(1, 1, 2); stageA(1, 1, 3);
    stageB(1, 1, 0); stageB(1, 1, 1);
    asm volatile("s_waitcnt vmcnt(6)" ::: "memory");
    __builtin_amdgcn_s_barrier();

    int ct = 0;
    for (int t = 0; t < NT; ++t) {
        bool st = (t + 2) < NT;
        int bs2 = (ct == 0) ? 2 : ct - 1;      // (ct+2)%3
        const bf16_t* Ac = As[ct];
        const bf16_t* Bc = Bs[ct];

        // k-slice 0 (+ half the t+2 staging)
        {
            int cof = (lq ^ sw) * 8;
            s16x8 af[4], bf4[4];
#pragma unroll
            for (int i = 0; i < 4; i++)
                af[i] = *(const s16x8*)&Ac[(wm + i * 16 + lr) * BK + cof];
#pragma unroll
            for (int i = 0; i < 4; i++)
                bf4[i] = *(const s16x8*)&Bc[(wn + i * 16 + lr) * BK + cof];
            if (st) { stageA(t + 2, bs2, 0); stageA(t + 2, bs2, 1); stageA(t + 2, bs2, 2); }
            __builtin_amdgcn_s_setprio(1);
#pragma unroll
            for (int tm = 0; tm < 4; tm++)
#pragma unroll
                for (int tn = 0; tn < 4; tn++)
                    acc[tm][tn] = __builtin_amdgcn_mfma_f32_16x16x32_bf16(
                        af[tm], bf4[tn], acc[tm][tn], 0, 0, 0);
            __builtin_amdgcn_s_setprio(0);
        }
        // k-slice 1 (+ other half of the staging)
        {
            int cof = ((4 | lq) ^ sw) * 8;
            s16x8 af[4], bf4[4];
#pragma unroll
            for (int i = 0; i < 4; i++)
                af[i] = *(const s16x8*)&Ac[(wm + i * 16 + lr) * BK + cof];
#pragma unroll
            for (int i = 0; i < 4; i++)
                bf4[i] = *(const s16x8*)&Bc[(wn + i * 16 + lr) * BK + cof];
            if (st) { stageA(t + 2, bs2, 3); stageB(t + 2, bs2, 0); stageB(t + 2, bs2, 1); }
            __builtin_amdgcn_s_setprio(1);
#pragma unroll
            for (int tm = 0; tm < 4; tm++)
#pragma unroll
                for (int tn = 0; tn < 4; tn++)
                    acc[tm][tn] = __builtin_amdgcn_mfma_f32_16x16x32_bf16(
                        af[tm], bf4[tn], acc[tm][tn], 0, 0, 0);
            __builtin_amdgcn_s_setprio(0);
        }

        // single per-tile gate (tile t+1 ready, buffer recycling safe)
        if (t < NT - 1) {
            if (st) asm volatile("s_waitcnt vmcnt(6)" ::: "memory");
            else    asm volatile("s_waitcnt vmcnt(0)" ::: "memory");
            __builtin_amdgcn_s_barrier();
        }
        ct = (ct == 2) ? 0 : ct + 1;
    }

    // epilogue
#pragma unroll
    for (int tm = 0; tm < 4; tm++) {
#pragma unroll
        for (int tn = 0; tn < 4; tn++) {
#pragma unroll
            for (int r = 0; r < 4; r++) {
                int mrow = bm + wm + tm * 16 + lq * 4 + r;
                int ncol = bn + wn + tn * 16 + lr;
                float vacc = acc[tm][tn][r];
                if (MODE == 1) {
                    vacc = (res[(size_t)mrow * N + ncol] + vacc) * scale;
                } else if (MODE == 2) {
                    vacc = gelu_fast(vacc + bias[ncol]);
                } else if (MODE == 3) {
                    vacc = (res[(size_t)mrow * N + ncol] + vacc + bias[ncol]) * scale;
                }
                if (OBF) ((bf16_t*)Cv)[(size_t)mrow * N + ncol] = f2bf(vacc);
                else     ((float*)Cv)[(size_t)mrow * N + ncol] = vacc;
            }
        }
    }
}

// ---------------------------------------------------------------------------
// Steps 4/7 kernel: same 3-buf counted-vmcnt 1-barrier loop at TM=64 x
// BN=128, 256 thr = 4 waves (2M x 2N, per-wave 32x64, acc[2][4]).
// LDS = 3 x (8 + 16) KiB = 72 KiB -> 2 blocks/CU: deep pipeline AND
// cross-block TLP (first config with both). Grid 1176, negligible tail.
// Same race ledger as gemm_fph (6 loads/tile, gate vmcnt(6)).
// ---------------------------------------------------------------------------
template <int MODE, bool OBF>
__global__ __launch_bounds__(256) void gemm_pipe3(
    const bf16_t* __restrict__ A, const bf16_t* __restrict__ B,
    void* __restrict__ Cv, int M, int N, int K,
    const float* __restrict__ bias, const float* __restrict__ res, float scale)
{
    constexpr int BM = 64, BN = 128, BK = 64, NBUF = 3;
    __shared__ __align__(16) bf16_t As[NBUF][BM * BK];   // 3 x 8 KiB
    __shared__ __align__(16) bf16_t Bs[NBUF][BN * BK];   // 3 x 16 KiB

    int tid  = threadIdx.x;
    int w    = tid >> 6;          // 0..3
    int lane = tid & 63;

    int mb = M / BM, nb = N / BN;
    int gblk = blockIdx.x;
    int full = mb & ~7;
    int gfull = full * nb;
    int m_, n_;
    if (gblk < gfull) {
        int sg = gblk / (8 * nb), u = gblk - sg * (8 * nb);
        m_ = sg * 8 + (u & 7); n_ = u >> 3;
    } else {
        int u = gblk - gfull, rem = mb - full;
        m_ = full + u % rem; n_ = u / rem;
    }
    int bm = m_ * BM, bn = n_ * BN;

    int wm = (w & 1) * 32;        // 2 M-waves
    int wn = (w >> 1) * 64;       // 2 N-waves
    int lr = lane & 15;
    int lq = lane >> 4;

    int srowl = lane >> 3;                    // 0..7
    int scb   = ((lane & 7) ^ srowl) * 16;    // swizzled source byte offset
    const char* Ab = (const char*)A;
    const char* Bb = (const char*)B;

    f32x4 acc[2][4] = {};

    // 256 lanes x 16 B = 32 rows per sweep. A: 2 sweeps, B: 4 sweeps.
    auto stageA = [&](int t, int bi, int j) {
        int rb = j * 32 + w * 8;
        GLOAD_LDS16(Ab + ((size_t)(bm + rb + srowl) * K + t * BK) * 2 + scb,
                    &As[bi][rb * BK]);
    };
    auto stageB = [&](int t, int bi, int j) {
        int rb = j * 32 + w * 8;
        GLOAD_LDS16(Bb + ((size_t)(bn + rb + srowl) * K + t * BK) * 2 + scb,
                    &Bs[bi][rb * BK]);
    };

    const int NT = K / BK;        // 12 or 48
    int sw = lr & 7;

    // prologue: tiles 0 and 1 staged (6 loads each); gate tile 0
    stageA(0, 0, 0); stageA(0, 0, 1);
    stageB(0, 0, 0); stageB(0, 0, 1); stageB(0, 0, 2); stageB(0, 0, 3);
    stageA(1, 1, 0); stageA(1, 1, 1);
    stageB(1, 1, 0); stageB(1, 1, 1); stageB(1, 1, 2); stageB(1, 1, 3);
    asm volatile("s_waitcnt vmcnt(6)" ::: "memory");
    __builtin_amdgcn_s_barrier();

    int ct = 0;
    for (int t = 0; t < NT; ++t) {
        bool st = (t + 2) < NT;
        int bs2 = (ct == 0) ? 2 : ct - 1;      // (ct+2)%3
        const bf16_t* Ac = As[ct];
        const bf16_t* Bc = Bs[ct];

        // k-slice 0
        {
            int cof = (lq ^ sw) * 8;
            s16x8 af[2], bf4[4];
#pragma unroll
            for (int i = 0; i < 2; i++)
                af[i] = *(const s16x8*)&Ac[(wm + i * 16 + lr) * BK + cof];
#pragma unroll
            for (int i = 0; i < 4; i++)
                bf4[i] = *(const s16x8*)&Bc[(wn + i * 16 + lr) * BK + cof];
            if (st) { stageA(t + 2, bs2, 0); stageA(t + 2, bs2, 1); stageB(t + 2, bs2, 0); }
            __builtin_amdgcn_s_setprio(1);
#pragma unroll
            for (int tm = 0; tm < 2; tm++)
#pragma unroll
                for (int tn = 0; tn < 4; tn++)
                    acc[tm][tn] = __builtin_amdgcn_mfma_f32_16x16x32_bf16(
                        af[tm], bf4[tn], acc[tm][tn], 0, 0, 0);
            __builtin_amdgcn_s_setprio(0);
        }
        // k-slice 1
        {
            int cof = ((4 | lq) ^ sw) * 8;
            s16x8 af[2], bf4[4];
#pragma unroll
            for (int i = 0; i < 2; i++)
                af[i] = *(const s16x8*)&Ac[(wm + i * 16 + lr) * BK + cof];
#pragma unroll
            for (int i = 0; i < 4; i++)
                bf4[i] = *(const s16x8*)&Bc[(wn + i * 16 + lr) * BK + cof];
            if (st) { stageB(t + 2, bs2, 1); stageB(t + 2, bs2, 2); stageB(t + 2, bs2, 3); }
            __builtin_amdgcn_s_setprio(1);
#pragma unroll
            for (int tm = 0; tm < 2; tm++)
#pragma unroll
                for (int tn = 0; tn < 4; tn++)
                    acc[tm][tn] = __builtin_amdgcn_mfma_f32_16x16x32_bf16(
                        af[tm], bf4[tn], acc[tm][tn], 0, 0, 0);
            __builtin_amdgcn_s_setprio(0);
        }

        if (t < NT - 1) {
            if (st) asm volatile("s_waitcnt vmcnt(6)" ::: "memory");
            else    asm volatile("s_waitcnt vmcnt(0)" ::: "memory");
            __builtin_amdgcn_s_barrier();
        }
        ct = (ct == 2) ? 0 : ct + 1;
    }

    // epilogue
#pragma unroll
    for (int tm = 0; tm < 2; tm++) {
#pragma unroll
        for (int tn = 0; tn < 4; tn++) {
#pragma unroll
            for (int r = 0; r < 4; r++) {
                int mrow = bm + wm + tm * 16 + lq * 4 + r;
                int ncol = bn + wn + tn * 16 + lr;
                float vacc = acc[tm][tn][r];
                if (MODE == 1) {
                    vacc = (res[(size_t)mrow * N + ncol] + vacc) * scale;
                } else if (MODE == 2) {
                    vacc = gelu_fast(vacc + bias[ncol]);
                } else if (MODE == 3) {
                    vacc = (res[(size_t)mrow * N + ncol] + vacc + bias[ncol]) * scale;
                }
                if (OBF) ((bf16_t*)Cv)[(size_t)mrow * N + ncol] = f2bf(vacc);
                else     ((float*)Cv)[(size_t)mrow * N + ncol] = vacc;
            }
        }
    }
}

// ---------------------------------------------------------------------------
// Launch
// ---------------------------------------------------------------------------
extern "C" void kernel_launch(void* const* d_in, const int* in_sizes, int n_in,
                              void* d_out, int out_size, void* d_ws, size_t ws_size,
                              hipStream_t stream)
{
    const float* x        = (const float*)d_in[0];
    const float* rel_bias = (const float*)d_in[1];
    const float* wq       = (const float*)d_in[2];
    const float* wk       = (const float*)d_in[3];
    const float* wv       = (const float*)d_in[4];
    const float* w_out    = (const float*)d_in[5];
    const float* ln1_g    = (const float*)d_in[6];
    const float* ln1_b    = (const float*)d_in[7];
    const float* ln2_g    = (const float*)d_in[8];
    const float* ln2_b    = (const float*)d_in[9];
    const float* w1       = (const float*)d_in[10];
    const float* b1       = (const float*)d_in[11];
    const float* w2       = (const float*)d_in[12];
    const float* b2       = (const float*)d_in[13];
    float* out = (float*)d_out;
    float* ws  = (float*)d_ws;

    const size_t SZ = (size_t)ROWS * HID;  // 9,633,792 floats
    // Region map (float units):
    //   [0, SZ/2)    o bf16; y2 bf16 [SZ/2, SZ)
    //   [SZ, 1.5SZ)  q bf16 (dies after attn)   } h bf16 [SZ,3SZ) after attn
    //   [2SZ, 2.5SZ) k bf16 (dies after attn)   }
    //   [3SZ, 3.5SZ) v bf16 (dies after attn)
    //   [4SZ, ...)   bf16 weights: wob 768x768, w1b 3072x768, w2b 768x3072
    bf16_t* q_bf = (bf16_t*)(ws + SZ);
    bf16_t* k_bf = (bf16_t*)(ws + 2 * SZ);
    bf16_t* v_bf = (bf16_t*)(ws + 3 * SZ);
    bf16_t* o_bf = (bf16_t*)ws;
    bf16_t* y2b  = (bf16_t*)(ws + SZ / 2);
    bf16_t* h    = (bf16_t*)(ws + SZ);
    bf16_t* wob  = (bf16_t*)(ws + 4 * SZ);
    bf16_t* w1b  = wob + (size_t)HID * HID;
    bf16_t* w2b  = w1b + (size_t)FFN * HID;

    // 0. weight conversions (one launch)
    cvt_w_kernel<<<(WOUT4 + 2 * W14 + 255) / 256, 256, 0, stream>>>(
        w_out, w1, w2, wob, w1b, w2b);

    // 1+2. fused LN1 + q,k,v per-head projections (MFMA, bf16 out)
    ln_qkv_mfma_kernel<<<ROWS / QKV_T, 256, 0, stream>>>(
        x, ln1_g, ln1_b, wq, wk, wv, q_bf, k_bf, v_bf);

    // 3. o = softmax((qk^T + bias)/sqrt(d)) @ v   (MFMA, bf16 out)
    attn_mfma_kernel<<<dim3(NHEAD, NB), 256, 0, stream>>>(q_bf, k_bf, v_bf, rel_bias, o_bf);

    // 4. x1 = (x + o @ w_out^T) * RATE   -> d_out (fp32)   [pipe3: 1176 blks]
    gemm_pipe3<1, false><<<(ROWS / 64) * (HID / 128), 256, 0, stream>>>(
        o_bf, wob, out, ROWS, HID, HID, nullptr, x, RATE);

    // 5. y2 = LN2(x1)  (bf16)
    ln_kernel<<<ROWS, 256, 0, stream>>>(out, ln2_g, ln2_b, y2b);

    // 6. h = gelu(y2 @ w1^T + b1)  (bf16)   [fph 1-barrier: 1176 blks]
    gemm_fph<2, true><<<(ROWS / 256) * (FFN / 128), 512, 0, stream>>>(
        y2b, w1b, h, ROWS, FFN, HID, b1, nullptr, 1.0f);

    // 7. out = (x1 + h @ w2^T + b2) * RATE  (fp32)   [pipe3: 1176 blks]
    gemm_pipe3<3, false><<<(ROWS / 64) * (HID / 128), 256, 0, stream>>>(
        h, w2b, out, ROWS, HID, FFN, b2, out, RATE);
}

// Round 6
// 434.399 us; speedup vs baseline: 1.0896x; 1.0896x over previous
//
#include <hip/hip_runtime.h>
#include <math.h>

// Problem constants
#define NB    64            // batch
#define LSEQ  196           // H*W = 14*14
#define HID   768
#define NHEAD 24
#define HDIM  32
#define FFN   3072
#define ROWS  (NB * LSEQ)   // 12544
#define RATE  0.2f
#define LN_EPS 1e-5f

typedef unsigned short bf16_t;                              // raw bf16 bits
typedef short s16x8 __attribute__((ext_vector_type(8)));    // 8 bf16 (4 VGPRs)
typedef float f32x4 __attribute__((ext_vector_type(4)));    // MFMA accumulator

// fp32 -> bf16 round-to-nearest-even (bit pattern in ushort)
__device__ __forceinline__ unsigned short f2bf(float f) {
    unsigned u = __float_as_uint(f);
    unsigned r = u + 0x7fffu + ((u >> 16) & 1u);
    return (unsigned short)(r >> 16);
}

// async global->LDS, 16 B per lane, dest = wave-uniform base + lane*16
#define GLOAD_LDS16(g, l)                                                  \
    __builtin_amdgcn_global_load_lds(                                      \
        (const __attribute__((address_space(1))) void*)(g),                \
        (__attribute__((address_space(3))) void*)(l), 16, 0, 0)

// ---------------------------------------------------------------------------
// fp32 -> bf16 convert for all three weight matrices in one launch.
// ---------------------------------------------------------------------------
#define WOUT4 (HID * HID / 4)
#define W14   (FFN * HID / 4)
__global__ __launch_bounds__(256) void cvt_w_kernel(
    const float* __restrict__ w_out, const float* __restrict__ w1,
    const float* __restrict__ w2, bf16_t* __restrict__ wob,
    bf16_t* __restrict__ w1b, bf16_t* __restrict__ w2b)
{
    int i = blockIdx.x * 256 + threadIdx.x;
    const float* src; bf16_t* dst; int off;
    if (i < WOUT4)            { src = w_out; dst = wob; off = i; }
    else if (i < WOUT4 + W14) { src = w1;    dst = w1b; off = i - WOUT4; }
    else                      { src = w2;    dst = w2b; off = i - WOUT4 - W14; }
    float4 v = ((const float4*)src)[off];
    uint2 p;
    p.x = (unsigned)f2bf(v.x) | ((unsigned)f2bf(v.y) << 16);
    p.y = (unsigned)f2bf(v.z) | ((unsigned)f2bf(v.w) << 16);
    ((uint2*)dst)[off] = p;
}

// ---------------------------------------------------------------------------
// LayerNorm over last dim (768), WAVE-PER-ROW (r6): one wave owns one row,
// shuffle-only reduction (no LDS, no __syncthreads). Grid ROWS/4, 256 thr.
// Replaces the 12544-block 8-sync LDS-tree version (serialization-bound).
// Same fp32 math; reduce pattern identical to ln_qkv (proven).
// ---------------------------------------------------------------------------
__global__ __launch_bounds__(256) void ln_wave_kernel(
    const float* __restrict__ x, const float* __restrict__ g,
    const float* __restrict__ b, bf16_t* __restrict__ yv)
{
    int w = threadIdx.x >> 6, lane = threadIdx.x & 63;
    size_t row = (size_t)blockIdx.x * 4 + w;
    const float4* xr = (const float4*)(x + row * HID);
    float4 xv[3];
    float s = 0.f, s2 = 0.f;
#pragma unroll
    for (int i = 0; i < 3; i++) {
        xv[i] = xr[lane + i * 64];
        s  += xv[i].x + xv[i].y + xv[i].z + xv[i].w;
        s2 += xv[i].x * xv[i].x + xv[i].y * xv[i].y
            + xv[i].z * xv[i].z + xv[i].w * xv[i].w;
    }
#pragma unroll
    for (int d = 1; d < 64; d <<= 1) {
        s  += __shfl_xor(s, d);
        s2 += __shfl_xor(s2, d);
    }
    float mean = s * (1.0f / HID);
    float rstd = rsqrtf(s2 * (1.0f / HID) - mean * mean + LN_EPS);
    uint2* yr = (uint2*)(yv + row * HID);
#pragma unroll
    for (int i = 0; i < 3; i++) {
        float4 gv = ((const float4*)g)[lane + i * 64];
        float4 bv = ((const float4*)b)[lane + i * 64];
        float o0 = (xv[i].x - mean) * rstd * gv.x + bv.x;
        float o1 = (xv[i].y - mean) * rstd * gv.y + bv.y;
        float o2 = (xv[i].z - mean) * rstd * gv.z + bv.z;
        float o3 = (xv[i].w - mean) * rstd * gv.w + bv.w;
        uint2 p;
        p.x = (unsigned)f2bf(o0) | ((unsigned)f2bf(o1) << 16);
        p.y = (unsigned)f2bf(o2) | ((unsigned)f2bf(o3) << 16);
        yr[lane + i * 64] = p;
    }
}

// ---------------------------------------------------------------------------
// Fused LN1 + QKV via MFMA. One block (256 thr = 4 waves) per 16 tokens.
// ---------------------------------------------------------------------------
#define QKV_T 16   // tokens per block
__global__ __launch_bounds__(256) void ln_qkv_mfma_kernel(
    const float* __restrict__ x, const float* __restrict__ g,
    const float* __restrict__ b,
    const float* __restrict__ wq, const float* __restrict__ wk,
    const float* __restrict__ wv,
    bf16_t* __restrict__ q, bf16_t* __restrict__ k, bf16_t* __restrict__ v)
{
    int tid = threadIdx.x;
    int w = tid >> 6, lane = tid & 63;
    int lr = lane & 15, lq = lane >> 4;

    __shared__ __align__(16) bf16_t Xs[QKV_T * 24 * 32];   // 24576 B
    __shared__ __align__(16) bf16_t Wqs[32 * 32];          //  2048 B x3
    __shared__ __align__(16) bf16_t Wks[32 * 32];
    __shared__ __align__(16) bf16_t Wvs[32 * 32];

    for (int i = tid; i < 1024; i += 256) {
        Wqs[i] = f2bf(wq[i]);
        Wks[i] = f2bf(wk[i]);
        Wvs[i] = f2bf(wv[i]);
    }

    float4 gv[3], bv[3];
#pragma unroll
    for (int i = 0; i < 3; i++) {
        gv[i] = ((const float4*)g)[lane + i * 64];
        bv[i] = ((const float4*)b)[lane + i * 64];
    }

    for (int j = 0; j < 4; j++) {
        int lt = w * 4 + j;
        size_t row = (size_t)blockIdx.x * QKV_T + lt;
        const float4* xr = (const float4*)(x + row * HID);
        float4 xv[3];
        float s = 0.f, s2 = 0.f;
#pragma unroll
        for (int i = 0; i < 3; i++) {
            xv[i] = xr[lane + i * 64];
            s  += xv[i].x + xv[i].y + xv[i].z + xv[i].w;
            s2 += xv[i].x * xv[i].x + xv[i].y * xv[i].y
                + xv[i].z * xv[i].z + xv[i].w * xv[i].w;
        }
#pragma unroll
        for (int d = 1; d < 64; d <<= 1) {
            s  += __shfl_xor(s, d);
            s2 += __shfl_xor(s2, d);
        }
        float mean = s * (1.0f / HID);
        float rstd = rsqrtf(s2 * (1.0f / HID) - mean * mean + LN_EPS);
#pragma unroll
        for (int i = 0; i < 3; i++) {
            int idx  = (lane + i * 64) * 4;
            int head = idx >> 5, d0 = idx & 31;
            float o0 = (xv[i].x - mean) * rstd * gv[i].x + bv[i].x;
            float o1 = (xv[i].y - mean) * rstd * gv[i].y + bv[i].y;
            float o2 = (xv[i].z - mean) * rstd * gv[i].z + bv[i].z;
            float o3 = (xv[i].w - mean) * rstd * gv[i].w + bv[i].w;
            uint2 p;
            p.x = (unsigned)f2bf(o0) | ((unsigned)f2bf(o1) << 16);
            p.y = (unsigned)f2bf(o2) | ((unsigned)f2bf(o3) << 16);
            *(uint2*)&Xs[(lt * 24 + head) * 32 + d0] = p;
        }
    }
    __syncthreads();

    s16x8 bq[2], bk[2], bvv[2];
    bq[0]  = *(const s16x8*)&Wqs[lr * 32 + lq * 8];
    bq[1]  = *(const s16x8*)&Wqs[(16 + lr) * 32 + lq * 8];
    bk[0]  = *(const s16x8*)&Wks[lr * 32 + lq * 8];
    bk[1]  = *(const s16x8*)&Wks[(16 + lr) * 32 + lq * 8];
    bvv[0] = *(const s16x8*)&Wvs[lr * 32 + lq * 8];
    bvv[1] = *(const s16x8*)&Wvs[(16 + lr) * 32 + lq * 8];

    for (int t = 0; t < 6; t++) {
        int tile = w * 6 + t;
        s16x8 aX = *(const s16x8*)&Xs[(tile * 16 + lr) * 32 + lq * 8];
        f32x4 z = {};
        f32x4 aq0 = __builtin_amdgcn_mfma_f32_16x16x32_bf16(aX, bq[0],  z, 0, 0, 0);
        f32x4 aq1 = __builtin_amdgcn_mfma_f32_16x16x32_bf16(aX, bq[1],  z, 0, 0, 0);
        f32x4 ak0 = __builtin_amdgcn_mfma_f32_16x16x32_bf16(aX, bk[0],  z, 0, 0, 0);
        f32x4 ak1 = __builtin_amdgcn_mfma_f32_16x16x32_bf16(aX, bk[1],  z, 0, 0, 0);
        f32x4 av0 = __builtin_amdgcn_mfma_f32_16x16x32_bf16(aX, bvv[0], z, 0, 0, 0);
        f32x4 av1 = __builtin_amdgcn_mfma_f32_16x16x32_bf16(aX, bvv[1], z, 0, 0, 0);
        int rbase = tile * 16 + lq * 4;
#pragma unroll
        for (int r = 0; r < 4; r++) {
            int xrow = rbase + r;
            int t_loc = xrow / 24, head = xrow - t_loc * 24;
            size_t gb = ((size_t)blockIdx.x * QKV_T + t_loc) * HID + head * 32;
            q[gb + lr]      = f2bf(aq0[r]);
            q[gb + 16 + lr] = f2bf(aq1[r]);
            k[gb + lr]      = f2bf(ak0[r]);
            k[gb + 16 + lr] = f2bf(ak1[r]);
            v[gb + lr]      = f2bf(av0[r]);
            v[gb + 16 + lr] = f2bf(av1[r]);
        }
    }
}

// ---------------------------------------------------------------------------
// MFMA attention: one block (256 thr = 4 waves) per (h, n). Unchanged.
// ---------------------------------------------------------------------------
#define VT_S 232   // V^T row stride (bf16)
#define P_S  40    // P row stride (bf16)

__global__ __launch_bounds__(256) void attn_mfma_kernel(
    const bf16_t* __restrict__ q, const bf16_t* __restrict__ k,
    const bf16_t* __restrict__ v, const float* __restrict__ rel_bias,
    bf16_t* __restrict__ o)
{
    int h = blockIdx.x;   // 0..23
    int n = blockIdx.y;   // 0..63
    int tid = threadIdx.x;
    int w = tid >> 6, lane = tid & 63;
    int lr = lane & 15;
    int lq = lane >> 4;

    __shared__ __align__(16) bf16_t Qs[208 * 32];
    __shared__ __align__(16) bf16_t Ks[224 * 32];
    __shared__ __align__(16) bf16_t Vt[32 * VT_S];
    __shared__ float bsh[28 * 28];
    __shared__ __align__(16) bf16_t Ps[4][16 * P_S];

    size_t base = (size_t)n * LSEQ * HID + (size_t)h * HDIM;

    for (int i = tid; i < 224 * 4; i += 256) {
        int r = i >> 2, c = i & 3;
        uint4 kv = make_uint4(0, 0, 0, 0);
        if (r < 196) kv = *(const uint4*)&k[base + (size_t)r * HID + c * 8];
        *(uint4*)&Ks[r * 32 + c * 8] = kv;
        if (r < 208) {
            uint4 qv = make_uint4(0, 0, 0, 0);
            if (r < 196) qv = *(const uint4*)&q[base + (size_t)r * HID + c * 8];
            *(uint4*)&Qs[r * 32 + c * 8] = qv;
        }
    }
    for (int i = tid; i < 196 * 16; i += 256) {
        int key = i >> 4, d2 = (i & 15) * 2;
        unsigned u = *(const unsigned*)&v[base + (size_t)key * HID + d2];
        Vt[d2 * VT_S + key]       = (bf16_t)(u & 0xffffu);
        Vt[(d2 + 1) * VT_S + key] = (bf16_t)(u >> 16);
    }
    for (int i = tid; i < 32 * 32; i += 256) {
        int d = i >> 5, kp = i & 31;
        if (kp < 28) Vt[d * VT_S + 196 + kp] = 0;
    }
    for (int i = tid; i < 784; i += 256) bsh[i] = rel_bias[i];
    __syncthreads();

    const float inv_sqrt_d = 0.17677669529663687f;
    bf16_t* P = Ps[w];

    for (int qt = w; qt < 13; qt += 4) {
        s16x8 aQ = *(const s16x8*)&Qs[(qt * 16 + lr) * 32 + lq * 8];

        int bb[4]; bool qvalid[4];
#pragma unroll
        for (int r = 0; r < 4; r++) {
            int qr = qt * 16 + lq * 4 + r;
            qvalid[r] = qr < LSEQ;
            int qq = qvalid[r] ? qr : 0;
            int qi = qq / 14, qj = qq - 14 * (qq / 14);
            bb[r] = (qi + 14) * 28 + (qj + 14);
        }

        f32x4 sf[14];
#pragma unroll
        for (int kt = 0; kt < 14; kt++) {
            s16x8 bK = *(const s16x8*)&Ks[(kt * 16 + lr) * 32 + lq * 8];
            f32x4 z = {};
            sf[kt] = __builtin_amdgcn_mfma_f32_16x16x32_bf16(aQ, bK, z, 0, 0, 0);
        }
#pragma unroll
        for (int kt = 0; kt < 14; kt++) {
            int key = kt * 16 + lr;
            bool kv = key < LSEQ;
            int kk2 = kv ? key : 0;
            int ip = kk2 / 14, jp = kk2 - 14 * ip;
            int boff = ip * 28 + jp;
#pragma unroll
            for (int r = 0; r < 4; r++) {
                float val = (sf[kt][r] + bsh[bb[r] - boff]) * inv_sqrt_d;
                sf[kt][r] = kv ? val : -1e30f;
            }
        }
        float mx[4];
#pragma unroll
        for (int r = 0; r < 4; r++) {
            float m = sf[0][r];
#pragma unroll
            for (int kt = 1; kt < 14; kt++) m = fmaxf(m, sf[kt][r]);
            mx[r] = m;
        }
#pragma unroll
        for (int d = 1; d < 16; d <<= 1)
#pragma unroll
            for (int r = 0; r < 4; r++)
                mx[r] = fmaxf(mx[r], __shfl_xor(mx[r], d));
        float sum[4] = {0.f, 0.f, 0.f, 0.f};
#pragma unroll
        for (int kt = 0; kt < 14; kt++)
#pragma unroll
            for (int r = 0; r < 4; r++) {
                float p = __expf(sf[kt][r] - mx[r]);
                sf[kt][r] = p;
                sum[r] += p;
            }
#pragma unroll
        for (int d = 1; d < 16; d <<= 1)
#pragma unroll
            for (int r = 0; r < 4; r++)
                sum[r] += __shfl_xor(sum[r], d);

        f32x4 oacc[2] = {};
#pragma unroll
        for (int kc = 0; kc < 7; kc++) {
#pragma unroll
            for (int r = 0; r < 4; r++) {
                P[(lq * 4 + r) * P_S + lr]      = f2bf(sf[2 * kc][r]);
                P[(lq * 4 + r) * P_S + 16 + lr] = f2bf(sf[2 * kc + 1][r]);
            }
            s16x8 aP = *(const s16x8*)&P[lr * P_S + lq * 8];
#pragma unroll
            for (int dt = 0; dt < 2; dt++) {
                s16x8 bV = *(const s16x8*)&Vt[(dt * 16 + lr) * VT_S + kc * 32 + lq * 8];
                oacc[dt] = __builtin_amdgcn_mfma_f32_16x16x32_bf16(aP, bV, oacc[dt], 0, 0, 0);
            }
        }
#pragma unroll
        for (int r = 0; r < 4; r++) {
            if (qvalid[r]) {
                float inv_l = 1.0f / sum[r];
                size_t ob = base + (size_t)(qt * 16 + lq * 4 + r) * HID;
                o[ob + lr]      = f2bf(oacc[0][r] * inv_l);
                o[ob + 16 + lr] = f2bf(oacc[1][r] * inv_l);
            }
        }
    }
}

// ---------------------------------------------------------------------------
// GELU helper
// ---------------------------------------------------------------------------
__device__ __forceinline__ float gelu_fast(float x) {
    // 0.5x(1+tanh(0.79788456(x+0.044715x^3))) = x - x/(e^{2z}+1)
    float z2 = 1.5957691216f * (x + 0.044715f * x * x * x);  // 2z
    return x - x * __frcp_rn(__expf(z2) + 1.0f);
}

// ---------------------------------------------------------------------------
// 2-phase double-buffered GEMM (r2 structure, measured best for steps 4/7:
// step7 ~95-100 us vs pipe3's 126 -- restored verbatim).
// ---------------------------------------------------------------------------
template <int MODE, bool OBF, int TM>
__global__ __launch_bounds__(256) void gemm_mfma(
    const bf16_t* __restrict__ A, const bf16_t* __restrict__ B,
    void* __restrict__ Cv, int M, int N, int K,
    const float* __restrict__ bias, const float* __restrict__ res, float scale)
{
    constexpr int MT = TM / 32;       // m-tiles per wave (4 or 2)
    __shared__ __align__(16) bf16_t As[2][TM * 64];    // 2 x (TM*128 B)
    __shared__ __align__(16) bf16_t Bs[2][128 * 64];   // 2 x 16 KiB

    int tid = threadIdx.x;
    int mb = M / TM, nb = N >> 7;
    int gblk = blockIdx.x;
    int full = mb & ~7;
    int gfull = full * nb;
    int m_, n_;
    if (gblk < gfull) {
        int sg = gblk / (8 * nb), u = gblk - sg * (8 * nb);
        m_ = sg * 8 + (u & 7); n_ = u >> 3;
    } else {
        int u = gblk - gfull, rem = mb - full;
        m_ = full + u % rem; n_ = u / rem;
    }
    int bm = m_ * TM, bn = n_ << 7;

    int w    = tid >> 6;
    int lane = tid & 63;
    int wm = (w & 1) * (TM / 2);
    int wn = (w >> 1) * 64;
    int lr = lane & 15;
    int lq = lane >> 4;

    int srowl = lane >> 3;                    // 0..7
    int scb   = ((lane & 7) ^ srowl) * 16;    // swizzled source byte offset
    const char* Ab = (const char*)A;
    const char* Bb = (const char*)B;

    f32x4 acc[MT][4] = {};

    auto stage = [&](int k0, int bi) {
#pragma unroll
        for (int j = 0; j < TM / 32; j++) {
            int rb = w * (TM / 4) + j * 8;
            GLOAD_LDS16(Ab + ((size_t)(bm + rb + srowl) * K + k0) * 2 + scb,
                        &As[bi][rb * 64]);
        }
#pragma unroll
        for (int j = 0; j < 4; j++) {
            int rb = w * 32 + j * 8;
            GLOAD_LDS16(Bb + ((size_t)(bn + rb + srowl) * K + k0) * 2 + scb,
                        &Bs[bi][rb * 64]);
        }
    };

    auto compute = [&](int bi) {
        int sw = lr & 7;
#pragma unroll
        for (int kc = 0; kc < 2; kc++) {
            int cof = (((kc << 2) | lq) ^ sw) * 8;
            s16x8 af[MT], bf[4];
#pragma unroll
            for (int t = 0; t < MT; t++)
                af[t] = *(const s16x8*)&As[bi][(wm + t * 16 + lr) * 64 + cof];
#pragma unroll
            for (int t = 0; t < 4; t++)
                bf[t] = *(const s16x8*)&Bs[bi][(wn + t * 16 + lr) * 64 + cof];
#pragma unroll
            for (int tm = 0; tm < MT; tm++)
#pragma unroll
                for (int tn = 0; tn < 4; tn++)
                    acc[tm][tn] = __builtin_amdgcn_mfma_f32_16x16x32_bf16(
                        af[tm], bf[tn], acc[tm][tn], 0, 0, 0);
        }
    };

    stage(0, 0);
    asm volatile("s_waitcnt vmcnt(0)" ::: "memory");
    __builtin_amdgcn_s_barrier();

    const int nt = K >> 6;
    int cur = 0;
    for (int t = 0; t < nt - 1; ++t) {
        stage((t + 1) << 6, cur ^ 1);   // issue next tile FIRST
        compute(cur);                   // latency hides under this
        asm volatile("s_waitcnt vmcnt(0)" ::: "memory");
        __builtin_amdgcn_s_barrier();
        cur ^= 1;
    }
    compute(cur);

#pragma unroll
    for (int tm = 0; tm < MT; tm++) {
#pragma unroll
        for (int tn = 0; tn < 4; tn++) {
#pragma unroll
            for (int r = 0; r < 4; r++) {
                int mrow = bm + wm + tm * 16 + lq * 4 + r;
                int ncol = bn + wn + tn * 16 + lr;
                float vacc = acc[tm][tn][r];
                if (MODE == 1) {
                    vacc = (res[(size_t)mrow * N + ncol] + vacc) * scale;
                } else if (MODE == 2) {
                    vacc = gelu_fast(vacc + bias[ncol]);
                } else if (MODE == 3) {
                    vacc = (res[(size_t)mrow * N + ncol] + vacc + bias[ncol]) * scale;
                }
                if (OBF) ((bf16_t*)Cv)[(size_t)mrow * N + ncol] = f2bf(vacc);
                else     ((float*)Cv)[(size_t)mrow * N + ncol] = vacc;
            }
        }
    }
}

// ---------------------------------------------------------------------------
// FFN1 kernel: r4-measured fine-phase pipeline (108.9 us), restored verbatim.
// BM=256 x BN=128, BK=64, 512 thr = 8 waves, 3 LDS buffers, 2 fine phases
// per K-tile, counted vmcnt(6) gate. (r5's barrier-minimal variant was ~null;
// this is the measured-best FFN1 structure.)
// ---------------------------------------------------------------------------
template <int MODE, bool OBF>
__global__ __launch_bounds__(512, 2) void gemm_fph(
    const bf16_t* __restrict__ A, const bf16_t* __restrict__ B,
    void* __restrict__ Cv, int M, int N, int K,
    const float* __restrict__ bias, const float* __restrict__ res, float scale)
{
    constexpr int BM = 256, BN = 128, BK = 64, NBUF = 3;
    __shared__ __align__(16) bf16_t As[NBUF][BM * BK];   // 3 x 32 KiB
    __shared__ __align__(16) bf16_t Bs[NBUF][BN * BK];   // 3 x 16 KiB

    int tid  = threadIdx.x;
    int w    = tid >> 6;          // 0..7
    int lane = tid & 63;

    int mb = M / BM, nb = N / BN;
    int gblk = blockIdx.x;
    int full = mb & ~7;
    int gfull = full * nb;
    int m_, n_;
    if (gblk < gfull) {
        int sg = gblk / (8 * nb), u = gblk - sg * (8 * nb);
        m_ = sg * 8 + (u & 7); n_ = u >> 3;
    } else {
        int u = gblk - gfull, rem = mb - full;
        m_ = full + u % rem; n_ = u / rem;
    }
    int bm = m_ * BM, bn = n_ * BN;

    int wm = (w >> 1) * 64;       // 4 M-waves
    int wn = (w & 1) * 64;        // 2 N-waves
    int lr = lane & 15;
    int lq = lane >> 4;

    int srowl = lane >> 3;                    // 0..7
    int scb   = ((lane & 7) ^ srowl) * 16;    // swizzled source byte offset
    const char* Ab = (const char*)A;
    const char* Bb = (const char*)B;

    f32x4 acc[4][4] = {};

    auto stageA = [&](int t, int bi, int j) {
        int rb = j * 64 + w * 8;
        GLOAD_LDS16(Ab + ((size_t)(bm + rb + srowl) * K + t * BK) * 2 + scb,
                    &As[bi][rb * BK]);
    };
    auto stageB = [&](int t, int bi, int j) {
        int rb = j * 64 + w * 8;
        GLOAD_LDS16(Bb + ((size_t)(bn + rb + srowl) * K + t * BK) * 2 + scb,
                    &Bs[bi][rb * BK]);
    };

    const int NT = K / BK;        // >= 3 here (12 or 48)
    int sw = lr & 7;

    // prologue: tiles 0 and 1 fully staged; gate tile 0
    stageA(0, 0, 0); stageA(0, 0, 1); stageA(0, 0, 2); stageA(0, 0, 3);
    stageB(0, 0, 0); stageB(0, 0, 1);
    stageA(1, 1, 0); stageA(1, 1, 1); stageA(1, 1, 2); stageA(1, 1, 3);
    stageB(1, 1, 0); stageB(1, 1, 1);
    asm volatile("s_waitcnt vmcnt(6)" ::: "memory");
    __builtin_amdgcn_s_barrier();

    for (int t = 0; t < NT; ++t) {
        int ct = t % 3;
        bool st = (t + 2) < NT;
        int bs2 = (t + 2) % 3;
        const bf16_t* Ac = As[ct];
        const bf16_t* Bc = Bs[ct];

        // ---------------- phase 0: k-slice 0 ----------------
        {
            int cof = ((lq) ^ sw) * 8;                    // kc=0
            s16x8 af[4], bf4[4];
#pragma unroll
            for (int i = 0; i < 4; i++)
                af[i] = *(const s16x8*)&Ac[(wm + i * 16 + lr) * BK + cof];
#pragma unroll
            for (int i = 0; i < 4; i++)
                bf4[i] = *(const s16x8*)&Bc[(wn + i * 16 + lr) * BK + cof];
            if (st) { stageA(t + 2, bs2, 0); stageA(t + 2, bs2, 1); stageA(t + 2, bs2, 2); }
            __builtin_amdgcn_s_barrier();
            __builtin_amdgcn_s_setprio(1);
#pragma unroll
            for (int tm = 0; tm < 4; tm++)
#pragma unroll
                for (int tn = 0; tn < 4; tn++)
                    acc[tm][tn] = __builtin_amdgcn_mfma_f32_16x16x32_bf16(
                        af[tm], bf4[tn], acc[tm][tn], 0, 0, 0);
            __builtin_amdgcn_s_setprio(0);
        }
        __builtin_amdgcn_s_barrier();

        // ---------------- phase 1: k-slice 1 ----------------
        {
            int cof = ((4 | lq) ^ sw) * 8;                // kc=1
            s16x8 af[4], bf4[4];
#pragma unroll
            for (int i = 0; i < 4; i++)
                af[i] = *(const s16x8*)&Ac[(wm + i * 16 + lr) * BK + cof];
#pragma unroll
            for (int i = 0; i < 4; i++)
                bf4[i] = *(const s16x8*)&Bc[(wn + i * 16 + lr) * BK + cof];
            if (st) { stageA(t + 2, bs2, 3); stageB(t + 2, bs2, 0); stageB(t + 2, bs2, 1); }
            __builtin_amdgcn_s_barrier();
            __builtin_amdgcn_s_setprio(1);
#pragma unroll
            for (int tm = 0; tm < 4; tm++)
#pragma unroll
                for (int tn = 0; tn < 4; tn++)
                    acc[tm][tn] = __builtin_amdgcn_mfma_f32_16x16x32_bf16(
                        af[tm], bf4[tn], acc[tm][tn], 0, 0, 0);
            __builtin_amdgcn_s_setprio(0);
        }

        // ---------------- per-K-tile gate for tile t+1 ----------------
        if (t < NT - 1) {
            if (st) asm volatile("s_waitcnt vmcnt(6)" ::: "memory");
            else    asm volatile("s_waitcnt vmcnt(0)" ::: "memory");
            __builtin_amdgcn_s_barrier();
        }
    }

    // epilogue
#pragma unroll
    for (int tm = 0; tm < 4; tm++) {
#pragma unroll
        for (int tn = 0; tn < 4; tn++) {
#pragma unroll
            for (int r = 0; r < 4; r++) {
                int mrow = bm + wm + tm * 16 + lq * 4 + r;
                int ncol = bn + wn + tn * 16 + lr;
                float vacc = acc[tm][tn][r];
                if (MODE == 1) {
                    vacc = (res[(size_t)mrow * N + ncol] + vacc) * scale;
                } else if (MODE == 2) {
                    vacc = gelu_fast(vacc + bias[ncol]);
                } else if (MODE == 3) {
                    vacc = (res[(size_t)mrow * N + ncol] + vacc + bias[ncol]) * scale;
                }
                if (OBF) ((bf16_t*)Cv)[(size_t)mrow * N + ncol] = f2bf(vacc);
                else     ((float*)Cv)[(size_t)mrow * N + ncol] = vacc;
            }
        }
    }
}

// ---------------------------------------------------------------------------
// Launch
// ---------------------------------------------------------------------------
extern "C" void kernel_launch(void* const* d_in, const int* in_sizes, int n_in,
                              void* d_out, int out_size, void* d_ws, size_t ws_size,
                              hipStream_t stream)
{
    const float* x        = (const float*)d_in[0];
    const float* rel_bias = (const float*)d_in[1];
    const float* wq       = (const float*)d_in[2];
    const float* wk       = (const float*)d_in[3];
    const float* wv       = (const float*)d_in[4];
    const float* w_out    = (const float*)d_in[5];
    const float* ln1_g    = (const float*)d_in[6];
    const float* ln1_b    = (const float*)d_in[7];
    const float* ln2_g    = (const float*)d_in[8];
    const float* ln2_b    = (const float*)d_in[9];
    const float* w1       = (const float*)d_in[10];
    const float* b1       = (const float*)d_in[11];
    const float* w2       = (const float*)d_in[12];
    const float* b2       = (const float*)d_in[13];
    float* out = (float*)d_out;
    float* ws  = (float*)d_ws;

    const size_t SZ = (size_t)ROWS * HID;  // 9,633,792 floats
    // Region map (float units):
    //   [0, SZ/2)    o bf16; y2 bf16 [SZ/2, SZ)
    //   [SZ, 1.5SZ)  q bf16 (dies after attn)   } h bf16 [SZ,3SZ) after attn
    //   [2SZ, 2.5SZ) k bf16 (dies after attn)   }
    //   [3SZ, 3.5SZ) v bf16 (dies after attn)
    //   [4SZ, ...)   bf16 weights: wob 768x768, w1b 3072x768, w2b 768x3072
    bf16_t* q_bf = (bf16_t*)(ws + SZ);
    bf16_t* k_bf = (bf16_t*)(ws + 2 * SZ);
    bf16_t* v_bf = (bf16_t*)(ws + 3 * SZ);
    bf16_t* o_bf = (bf16_t*)ws;
    bf16_t* y2b  = (bf16_t*)(ws + SZ / 2);
    bf16_t* h    = (bf16_t*)(ws + SZ);
    bf16_t* wob  = (bf16_t*)(ws + 4 * SZ);
    bf16_t* w1b  = wob + (size_t)HID * HID;
    bf16_t* w2b  = w1b + (size_t)FFN * HID;

    // 0. weight conversions (one launch)
    cvt_w_kernel<<<(WOUT4 + 2 * W14 + 255) / 256, 256, 0, stream>>>(
        w_out, w1, w2, wob, w1b, w2b);

    // 1+2. fused LN1 + q,k,v per-head projections (MFMA, bf16 out)
    ln_qkv_mfma_kernel<<<ROWS / QKV_T, 256, 0, stream>>>(
        x, ln1_g, ln1_b, wq, wk, wv, q_bf, k_bf, v_bf);

    // 3. o = softmax((qk^T + bias)/sqrt(d)) @ v   (MFMA, bf16 out)
    attn_mfma_kernel<<<dim3(NHEAD, NB), 256, 0, stream>>>(q_bf, k_bf, v_bf, rel_bias, o_bf);

    // 4. x1 = (x + o @ w_out^T) * RATE   -> d_out (fp32)   [r2 dbuf TM=64]
    gemm_mfma<1, false, 64><<<(ROWS / 64) * (HID / 128), 256, 0, stream>>>(
        o_bf, wob, out, ROWS, HID, HID, nullptr, x, RATE);

    // 5. y2 = LN2(x1)  (bf16)   [wave-per-row, shuffle-only: 3136 blks]
    ln_wave_kernel<<<ROWS / 4, 256, 0, stream>>>(out, ln2_g, ln2_b, y2b);

    // 6. h = gelu(y2 @ w1^T + b1)  (bf16)   [r4 fph: 1176 blks]
    gemm_fph<2, true><<<(ROWS / 256) * (FFN / 128), 512, 0, stream>>>(
        y2b, w1b, h, ROWS, FFN, HID, b1, nullptr, 1.0f);

    // 7. out = (x1 + h @ w2^T + b2) * RATE  (fp32)   [r2 dbuf TM=64]
    gemm_mfma<3, false, 64><<<(ROWS / 64) * (HID / 128), 256, 0, stream>>>(
        h, w2b, out, ROWS, HID, FFN, b2, out, RATE);
}

// Round 7
// 431.009 us; speedup vs baseline: 1.0982x; 1.0079x over previous
//
#include <hip/hip_runtime.h>
#include <math.h>

// Problem constants
#define NB    64            // batch
#define LSEQ  196           // H*W = 14*14
#define HID   768
#define NHEAD 24
#define HDIM  32
#define FFN   3072
#define ROWS  (NB * LSEQ)   // 12544
#define RATE  0.2f
#define LN_EPS 1e-5f

typedef unsigned short bf16_t;                              // raw bf16 bits
typedef short s16x8 __attribute__((ext_vector_type(8)));    // 8 bf16 (4 VGPRs)
typedef float f32x4 __attribute__((ext_vector_type(4)));    // MFMA accumulator

// fp32 -> bf16 round-to-nearest-even (bit pattern in ushort)
__device__ __forceinline__ unsigned short f2bf(float f) {
    unsigned u = __float_as_uint(f);
    unsigned r = u + 0x7fffu + ((u >> 16) & 1u);
    return (unsigned short)(r >> 16);
}

// async global->LDS, 16 B per lane, dest = wave-uniform base + lane*16
#define GLOAD_LDS16(g, l)                                                  \
    __builtin_amdgcn_global_load_lds(                                      \
        (const __attribute__((address_space(1))) void*)(g),                \
        (__attribute__((address_space(3))) void*)(l), 16, 0, 0)

// ---------------------------------------------------------------------------
// fp32 -> bf16 convert for all three weight matrices in one launch.
// ---------------------------------------------------------------------------
#define WOUT4 (HID * HID / 4)
#define W14   (FFN * HID / 4)
__global__ __launch_bounds__(256) void cvt_w_kernel(
    const float* __restrict__ w_out, const float* __restrict__ w1,
    const float* __restrict__ w2, bf16_t* __restrict__ wob,
    bf16_t* __restrict__ w1b, bf16_t* __restrict__ w2b)
{
    int i = blockIdx.x * 256 + threadIdx.x;
    const float* src; bf16_t* dst; int off;
    if (i < WOUT4)            { src = w_out; dst = wob; off = i; }
    else if (i < WOUT4 + W14) { src = w1;    dst = w1b; off = i - WOUT4; }
    else                      { src = w2;    dst = w2b; off = i - WOUT4 - W14; }
    float4 v = ((const float4*)src)[off];
    uint2 p;
    p.x = (unsigned)f2bf(v.x) | ((unsigned)f2bf(v.y) << 16);
    p.y = (unsigned)f2bf(v.z) | ((unsigned)f2bf(v.w) << 16);
    ((uint2*)dst)[off] = p;
}

// ---------------------------------------------------------------------------
// LayerNorm over last dim (768), WAVE-PER-ROW: one wave owns one row,
// shuffle-only reduction (no LDS, no __syncthreads). Grid ROWS/4, 256 thr.
// ---------------------------------------------------------------------------
__global__ __launch_bounds__(256) void ln_wave_kernel(
    const float* __restrict__ x, const float* __restrict__ g,
    const float* __restrict__ b, bf16_t* __restrict__ yv)
{
    int w = threadIdx.x >> 6, lane = threadIdx.x & 63;
    size_t row = (size_t)blockIdx.x * 4 + w;
    const float4* xr = (const float4*)(x + row * HID);
    float4 xv[3];
    float s = 0.f, s2 = 0.f;
#pragma unroll
    for (int i = 0; i < 3; i++) {
        xv[i] = xr[lane + i * 64];
        s  += xv[i].x + xv[i].y + xv[i].z + xv[i].w;
        s2 += xv[i].x * xv[i].x + xv[i].y * xv[i].y
            + xv[i].z * xv[i].z + xv[i].w * xv[i].w;
    }
#pragma unroll
    for (int d = 1; d < 64; d <<= 1) {
        s  += __shfl_xor(s, d);
        s2 += __shfl_xor(s2, d);
    }
    float mean = s * (1.0f / HID);
    float rstd = rsqrtf(s2 * (1.0f / HID) - mean * mean + LN_EPS);
    uint2* yr = (uint2*)(yv + row * HID);
#pragma unroll
    for (int i = 0; i < 3; i++) {
        float4 gv = ((const float4*)g)[lane + i * 64];
        float4 bv = ((const float4*)b)[lane + i * 64];
        float o0 = (xv[i].x - mean) * rstd * gv.x + bv.x;
        float o1 = (xv[i].y - mean) * rstd * gv.y + bv.y;
        float o2 = (xv[i].z - mean) * rstd * gv.z + bv.z;
        float o3 = (xv[i].w - mean) * rstd * gv.w + bv.w;
        uint2 p;
        p.x = (unsigned)f2bf(o0) | ((unsigned)f2bf(o1) << 16);
        p.y = (unsigned)f2bf(o2) | ((unsigned)f2bf(o3) << 16);
        yr[lane + i * 64] = p;
    }
}

// ---------------------------------------------------------------------------
// Fused LN1 + QKV via MFMA. One block (256 thr = 4 waves) per 16 tokens.
// ---------------------------------------------------------------------------
#define QKV_T 16   // tokens per block
__global__ __launch_bounds__(256) void ln_qkv_mfma_kernel(
    const float* __restrict__ x, const float* __restrict__ g,
    const float* __restrict__ b,
    const float* __restrict__ wq, const float* __restrict__ wk,
    const float* __restrict__ wv,
    bf16_t* __restrict__ q, bf16_t* __restrict__ k, bf16_t* __restrict__ v)
{
    int tid = threadIdx.x;
    int w = tid >> 6, lane = tid & 63;
    int lr = lane & 15, lq = lane >> 4;

    __shared__ __align__(16) bf16_t Xs[QKV_T * 24 * 32];   // 24576 B
    __shared__ __align__(16) bf16_t Wqs[32 * 32];          //  2048 B x3
    __shared__ __align__(16) bf16_t Wks[32 * 32];
    __shared__ __align__(16) bf16_t Wvs[32 * 32];

    for (int i = tid; i < 1024; i += 256) {
        Wqs[i] = f2bf(wq[i]);
        Wks[i] = f2bf(wk[i]);
        Wvs[i] = f2bf(wv[i]);
    }

    float4 gv[3], bv[3];
#pragma unroll
    for (int i = 0; i < 3; i++) {
        gv[i] = ((const float4*)g)[lane + i * 64];
        bv[i] = ((const float4*)b)[lane + i * 64];
    }

    for (int j = 0; j < 4; j++) {
        int lt = w * 4 + j;
        size_t row = (size_t)blockIdx.x * QKV_T + lt;
        const float4* xr = (const float4*)(x + row * HID);
        float4 xv[3];
        float s = 0.f, s2 = 0.f;
#pragma unroll
        for (int i = 0; i < 3; i++) {
            xv[i] = xr[lane + i * 64];
            s  += xv[i].x + xv[i].y + xv[i].z + xv[i].w;
            s2 += xv[i].x * xv[i].x + xv[i].y * xv[i].y
                + xv[i].z * xv[i].z + xv[i].w * xv[i].w;
        }
#pragma unroll
        for (int d = 1; d < 64; d <<= 1) {
            s  += __shfl_xor(s, d);
            s2 += __shfl_xor(s2, d);
        }
        float mean = s * (1.0f / HID);
        float rstd = rsqrtf(s2 * (1.0f / HID) - mean * mean + LN_EPS);
#pragma unroll
        for (int i = 0; i < 3; i++) {
            int idx  = (lane + i * 64) * 4;
            int head = idx >> 5, d0 = idx & 31;
            float o0 = (xv[i].x - mean) * rstd * gv[i].x + bv[i].x;
            float o1 = (xv[i].y - mean) * rstd * gv[i].y + bv[i].y;
            float o2 = (xv[i].z - mean) * rstd * gv[i].z + bv[i].z;
            float o3 = (xv[i].w - mean) * rstd * gv[i].w + bv[i].w;
            uint2 p;
            p.x = (unsigned)f2bf(o0) | ((unsigned)f2bf(o1) << 16);
            p.y = (unsigned)f2bf(o2) | ((unsigned)f2bf(o3) << 16);
            *(uint2*)&Xs[(lt * 24 + head) * 32 + d0] = p;
        }
    }
    __syncthreads();

    s16x8 bq[2], bk[2], bvv[2];
    bq[0]  = *(const s16x8*)&Wqs[lr * 32 + lq * 8];
    bq[1]  = *(const s16x8*)&Wqs[(16 + lr) * 32 + lq * 8];
    bk[0]  = *(const s16x8*)&Wks[lr * 32 + lq * 8];
    bk[1]  = *(const s16x8*)&Wks[(16 + lr) * 32 + lq * 8];
    bvv[0] = *(const s16x8*)&Wvs[lr * 32 + lq * 8];
    bvv[1] = *(const s16x8*)&Wvs[(16 + lr) * 32 + lq * 8];

    for (int t = 0; t < 6; t++) {
        int tile = w * 6 + t;
        s16x8 aX = *(const s16x8*)&Xs[(tile * 16 + lr) * 32 + lq * 8];
        f32x4 z = {};
        f32x4 aq0 = __builtin_amdgcn_mfma_f32_16x16x32_bf16(aX, bq[0],  z, 0, 0, 0);
        f32x4 aq1 = __builtin_amdgcn_mfma_f32_16x16x32_bf16(aX, bq[1],  z, 0, 0, 0);
        f32x4 ak0 = __builtin_amdgcn_mfma_f32_16x16x32_bf16(aX, bk[0],  z, 0, 0, 0);
        f32x4 ak1 = __builtin_amdgcn_mfma_f32_16x16x32_bf16(aX, bk[1],  z, 0, 0, 0);
        f32x4 av0 = __builtin_amdgcn_mfma_f32_16x16x32_bf16(aX, bvv[0], z, 0, 0, 0);
        f32x4 av1 = __builtin_amdgcn_mfma_f32_16x16x32_bf16(aX, bvv[1], z, 0, 0, 0);
        int rbase = tile * 16 + lq * 4;
#pragma unroll
        for (int r = 0; r < 4; r++) {
            int xrow = rbase + r;
            int t_loc = xrow / 24, head = xrow - t_loc * 24;
            size_t gb = ((size_t)blockIdx.x * QKV_T + t_loc) * HID + head * 32;
            q[gb + lr]      = f2bf(aq0[r]);
            q[gb + 16 + lr] = f2bf(aq1[r]);
            k[gb + lr]      = f2bf(ak0[r]);
            k[gb + 16 + lr] = f2bf(ak1[r]);
            v[gb + lr]      = f2bf(av0[r]);
            v[gb + 16 + lr] = f2bf(av1[r]);
        }
    }
}

// ---------------------------------------------------------------------------
// MFMA attention: one block (256 thr = 4 waves) per (h, n).
// r7 trim: 13 key-tiles (208 keys >= 196) instead of 14 -- the 14th tile was
// fully masked work (QK MFMA + softmax VALU on -1e30 lanes). Ks shrunk to
// 208 rows. PV stays a 7-pair loop: pair 6's second half-tile P is written
// as exact zeros (V rows 208..223 already zeroed), preserving layout.
// ---------------------------------------------------------------------------
#define VT_S 232   // V^T row stride (bf16)
#define P_S  40    // P row stride (bf16)

__global__ __launch_bounds__(256) void attn_mfma_kernel(
    const bf16_t* __restrict__ q, const bf16_t* __restrict__ k,
    const bf16_t* __restrict__ v, const float* __restrict__ rel_bias,
    bf16_t* __restrict__ o)
{
    int h = blockIdx.x;   // 0..23
    int n = blockIdx.y;   // 0..63
    int tid = threadIdx.x;
    int w = tid >> 6, lane = tid & 63;
    int lr = lane & 15;
    int lq = lane >> 4;

    __shared__ __align__(16) bf16_t Qs[208 * 32];
    __shared__ __align__(16) bf16_t Ks[208 * 32];
    __shared__ __align__(16) bf16_t Vt[32 * VT_S];
    __shared__ float bsh[28 * 28];
    __shared__ __align__(16) bf16_t Ps[4][16 * P_S];

    size_t base = (size_t)n * LSEQ * HID + (size_t)h * HDIM;

    for (int i = tid; i < 208 * 4; i += 256) {
        int r = i >> 2, c = i & 3;
        uint4 kv = make_uint4(0, 0, 0, 0);
        uint4 qv = make_uint4(0, 0, 0, 0);
        if (r < 196) {
            kv = *(const uint4*)&k[base + (size_t)r * HID + c * 8];
            qv = *(const uint4*)&q[base + (size_t)r * HID + c * 8];
        }
        *(uint4*)&Ks[r * 32 + c * 8] = kv;
        *(uint4*)&Qs[r * 32 + c * 8] = qv;
    }
    for (int i = tid; i < 196 * 16; i += 256) {
        int key = i >> 4, d2 = (i & 15) * 2;
        unsigned u = *(const unsigned*)&v[base + (size_t)key * HID + d2];
        Vt[d2 * VT_S + key]       = (bf16_t)(u & 0xffffu);
        Vt[(d2 + 1) * VT_S + key] = (bf16_t)(u >> 16);
    }
    for (int i = tid; i < 32 * 32; i += 256) {
        int d = i >> 5, kp = i & 31;
        if (kp < 28) Vt[d * VT_S + 196 + kp] = 0;
    }
    for (int i = tid; i < 784; i += 256) bsh[i] = rel_bias[i];
    __syncthreads();

    const float inv_sqrt_d = 0.17677669529663687f;
    bf16_t* P = Ps[w];

    for (int qt = w; qt < 13; qt += 4) {
        s16x8 aQ = *(const s16x8*)&Qs[(qt * 16 + lr) * 32 + lq * 8];

        int bb[4]; bool qvalid[4];
#pragma unroll
        for (int r = 0; r < 4; r++) {
            int qr = qt * 16 + lq * 4 + r;
            qvalid[r] = qr < LSEQ;
            int qq = qvalid[r] ? qr : 0;
            int qi = qq / 14, qj = qq - 14 * (qq / 14);
            bb[r] = (qi + 14) * 28 + (qj + 14);
        }

        f32x4 sf[13];
#pragma unroll
        for (int kt = 0; kt < 13; kt++) {
            s16x8 bK = *(const s16x8*)&Ks[(kt * 16 + lr) * 32 + lq * 8];
            f32x4 z = {};
            sf[kt] = __builtin_amdgcn_mfma_f32_16x16x32_bf16(aQ, bK, z, 0, 0, 0);
        }
#pragma unroll
        for (int kt = 0; kt < 13; kt++) {
            int key = kt * 16 + lr;
            bool kv = key < LSEQ;
            int kk2 = kv ? key : 0;
            int ip = kk2 / 14, jp = kk2 - 14 * ip;
            int boff = ip * 28 + jp;
#pragma unroll
            for (int r = 0; r < 4; r++) {
                float val = (sf[kt][r] + bsh[bb[r] - boff]) * inv_sqrt_d;
                sf[kt][r] = kv ? val : -1e30f;
            }
        }
        float mx[4];
#pragma unroll
        for (int r = 0; r < 4; r++) {
            float m = sf[0][r];
#pragma unroll
            for (int kt = 1; kt < 13; kt++) m = fmaxf(m, sf[kt][r]);
            mx[r] = m;
        }
#pragma unroll
        for (int d = 1; d < 16; d <<= 1)
#pragma unroll
            for (int r = 0; r < 4; r++)
                mx[r] = fmaxf(mx[r], __shfl_xor(mx[r], d));
        float sum[4] = {0.f, 0.f, 0.f, 0.f};
#pragma unroll
        for (int kt = 0; kt < 13; kt++)
#pragma unroll
            for (int r = 0; r < 4; r++) {
                float p = __expf(sf[kt][r] - mx[r]);
                sf[kt][r] = p;
                sum[r] += p;
            }
#pragma unroll
        for (int d = 1; d < 16; d <<= 1)
#pragma unroll
            for (int r = 0; r < 4; r++)
                sum[r] += __shfl_xor(sum[r], d);

        f32x4 oacc[2] = {};
#pragma unroll
        for (int kc = 0; kc < 7; kc++) {
#pragma unroll
            for (int r = 0; r < 4; r++) {
                P[(lq * 4 + r) * P_S + lr]      = f2bf(sf[2 * kc][r]);
                P[(lq * 4 + r) * P_S + 16 + lr] =
                    (kc < 6) ? f2bf(sf[2 * kc + 1][r]) : (bf16_t)0;
            }
            s16x8 aP = *(const s16x8*)&P[lr * P_S + lq * 8];
#pragma unroll
            for (int dt = 0; dt < 2; dt++) {
                s16x8 bV = *(const s16x8*)&Vt[(dt * 16 + lr) * VT_S + kc * 32 + lq * 8];
                oacc[dt] = __builtin_amdgcn_mfma_f32_16x16x32_bf16(aP, bV, oacc[dt], 0, 0, 0);
            }
        }
#pragma unroll
        for (int r = 0; r < 4; r++) {
            if (qvalid[r]) {
                float inv_l = 1.0f / sum[r];
                size_t ob = base + (size_t)(qt * 16 + lq * 4 + r) * HID;
                o[ob + lr]      = f2bf(oacc[0][r] * inv_l);
                o[ob + 16 + lr] = f2bf(oacc[1][r] * inv_l);
            }
        }
    }
}

// ---------------------------------------------------------------------------
// GELU helper
// ---------------------------------------------------------------------------
__device__ __forceinline__ float gelu_fast(float x) {
    // 0.5x(1+tanh(0.79788456(x+0.044715x^3))) = x - x/(e^{2z}+1)
    float z2 = 1.5957691216f * (x + 0.044715f * x * x * x);  // 2z
    return x - x * __frcp_rn(__expf(z2) + 1.0f);
}

// ---------------------------------------------------------------------------
// 2-phase double-buffered GEMM (r2 structure, measured best for steps 4/7).
// ---------------------------------------------------------------------------
template <int MODE, bool OBF, int TM>
__global__ __launch_bounds__(256) void gemm_mfma(
    const bf16_t* __restrict__ A, const bf16_t* __restrict__ B,
    void* __restrict__ Cv, int M, int N, int K,
    const float* __restrict__ bias, const float* __restrict__ res, float scale)
{
    constexpr int MT = TM / 32;       // m-tiles per wave (4 or 2)
    __shared__ __align__(16) bf16_t As[2][TM * 64];    // 2 x (TM*128 B)
    __shared__ __align__(16) bf16_t Bs[2][128 * 64];   // 2 x 16 KiB

    int tid = threadIdx.x;
    int mb = M / TM, nb = N >> 7;
    int gblk = blockIdx.x;
    int full = mb & ~7;
    int gfull = full * nb;
    int m_, n_;
    if (gblk < gfull) {
        int sg = gblk / (8 * nb), u = gblk - sg * (8 * nb);
        m_ = sg * 8 + (u & 7); n_ = u >> 3;
    } else {
        int u = gblk - gfull, rem = mb - full;
        m_ = full + u % rem; n_ = u / rem;
    }
    int bm = m_ * TM, bn = n_ << 7;

    int w    = tid >> 6;
    int lane = tid & 63;
    int wm = (w & 1) * (TM / 2);
    int wn = (w >> 1) * 64;
    int lr = lane & 15;
    int lq = lane >> 4;

    int srowl = lane >> 3;                    // 0..7
    int scb   = ((lane & 7) ^ srowl) * 16;    // swizzled source byte offset
    const char* Ab = (const char*)A;
    const char* Bb = (const char*)B;

    f32x4 acc[MT][4] = {};

    auto stage = [&](int k0, int bi) {
#pragma unroll
        for (int j = 0; j < TM / 32; j++) {
            int rb = w * (TM / 4) + j * 8;
            GLOAD_LDS16(Ab + ((size_t)(bm + rb + srowl) * K + k0) * 2 + scb,
                        &As[bi][rb * 64]);
        }
#pragma unroll
        for (int j = 0; j < 4; j++) {
            int rb = w * 32 + j * 8;
            GLOAD_LDS16(Bb + ((size_t)(bn + rb + srowl) * K + k0) * 2 + scb,
                        &Bs[bi][rb * 64]);
        }
    };

    auto compute = [&](int bi) {
        int sw = lr & 7;
#pragma unroll
        for (int kc = 0; kc < 2; kc++) {
            int cof = (((kc << 2) | lq) ^ sw) * 8;
            s16x8 af[MT], bf[4];
#pragma unroll
            for (int t = 0; t < MT; t++)
                af[t] = *(const s16x8*)&As[bi][(wm + t * 16 + lr) * 64 + cof];
#pragma unroll
            for (int t = 0; t < 4; t++)
                bf[t] = *(const s16x8*)&Bs[bi][(wn + t * 16 + lr) * 64 + cof];
#pragma unroll
            for (int tm = 0; tm < MT; tm++)
#pragma unroll
                for (int tn = 0; tn < 4; tn++)
                    acc[tm][tn] = __builtin_amdgcn_mfma_f32_16x16x32_bf16(
                        af[tm], bf[tn], acc[tm][tn], 0, 0, 0);
        }
    };

    stage(0, 0);
    asm volatile("s_waitcnt vmcnt(0)" ::: "memory");
    __builtin_amdgcn_s_barrier();

    const int nt = K >> 6;
    int cur = 0;
    for (int t = 0; t < nt - 1; ++t) {
        stage((t + 1) << 6, cur ^ 1);   // issue next tile FIRST
        compute(cur);                   // latency hides under this
        asm volatile("s_waitcnt vmcnt(0)" ::: "memory");
        __builtin_amdgcn_s_barrier();
        cur ^= 1;
    }
    compute(cur);

#pragma unroll
    for (int tm = 0; tm < MT; tm++) {
#pragma unroll
        for (int tn = 0; tn < 4; tn++) {
#pragma unroll
            for (int r = 0; r < 4; r++) {
                int mrow = bm + wm + tm * 16 + lq * 4 + r;
                int ncol = bn + wn + tn * 16 + lr;
                float vacc = acc[tm][tn][r];
                if (MODE == 1) {
                    vacc = (res[(size_t)mrow * N + ncol] + vacc) * scale;
                } else if (MODE == 2) {
                    vacc = gelu_fast(vacc + bias[ncol]);
                } else if (MODE == 3) {
                    vacc = (res[(size_t)mrow * N + ncol] + vacc + bias[ncol]) * scale;
                }
                if (OBF) ((bf16_t*)Cv)[(size_t)mrow * N + ncol] = f2bf(vacc);
                else     ((float*)Cv)[(size_t)mrow * N + ncol] = vacc;
            }
        }
    }
}

// ---------------------------------------------------------------------------
// FFN1 kernel: r4-measured fine-phase pipeline (107.5 us r6), unchanged.
// ---------------------------------------------------------------------------
template <int MODE, bool OBF>
__global__ __launch_bounds__(512, 2) void gemm_fph(
    const bf16_t* __restrict__ A, const bf16_t* __restrict__ B,
    void* __restrict__ Cv, int M, int N, int K,
    const float* __restrict__ bias, const float* __restrict__ res, float scale)
{
    constexpr int BM = 256, BN = 128, BK = 64, NBUF = 3;
    __shared__ __align__(16) bf16_t As[NBUF][BM * BK];   // 3 x 32 KiB
    __shared__ __align__(16) bf16_t Bs[NBUF][BN * BK];   // 3 x 16 KiB

    int tid  = threadIdx.x;
    int w    = tid >> 6;          // 0..7
    int lane = tid & 63;

    int mb = M / BM, nb = N / BN;
    int gblk = blockIdx.x;
    int full = mb & ~7;
    int gfull = full * nb;
    int m_, n_;
    if (gblk < gfull) {
        int sg = gblk / (8 * nb), u = gblk - sg * (8 * nb);
        m_ = sg * 8 + (u & 7); n_ = u >> 3;
    } else {
        int u = gblk - gfull, rem = mb - full;
        m_ = full + u % rem; n_ = u / rem;
    }
    int bm = m_ * BM, bn = n_ * BN;

    int wm = (w >> 1) * 64;       // 4 M-waves
    int wn = (w & 1) * 64;        // 2 N-waves
    int lr = lane & 15;
    int lq = lane >> 4;

    int srowl = lane >> 3;                    // 0..7
    int scb   = ((lane & 7) ^ srowl) * 16;    // swizzled source byte offset
    const char* Ab = (const char*)A;
    const char* Bb = (const char*)B;

    f32x4 acc[4][4] = {};

    auto stageA = [&](int t, int bi, int j) {
        int rb = j * 64 + w * 8;
        GLOAD_LDS16(Ab + ((size_t)(bm + rb + srowl) * K + t * BK) * 2 + scb,
                    &As[bi][rb * BK]);
    };
    auto stageB = [&](int t, int bi, int j) {
        int rb = j * 64 + w * 8;
        GLOAD_LDS16(Bb + ((size_t)(bn + rb + srowl) * K + t * BK) * 2 + scb,
                    &Bs[bi][rb * BK]);
    };

    const int NT = K / BK;        // >= 3 here (12 or 48)
    int sw = lr & 7;

    // prologue: tiles 0 and 1 fully staged; gate tile 0
    stageA(0, 0, 0); stageA(0, 0, 1); stageA(0, 0, 2); stageA(0, 0, 3);
    stageB(0, 0, 0); stageB(0, 0, 1);
    stageA(1, 1, 0); stageA(1, 1, 1); stageA(1, 1, 2); stageA(1, 1, 3);
    stageB(1, 1, 0); stageB(1, 1, 1);
    asm volatile("s_waitcnt vmcnt(6)" ::: "memory");
    __builtin_amdgcn_s_barrier();

    for (int t = 0; t < NT; ++t) {
        int ct = t % 3;
        bool st = (t + 2) < NT;
        int bs2 = (t + 2) % 3;
        const bf16_t* Ac = As[ct];
        const bf16_t* Bc = Bs[ct];

        // ---------------- phase 0: k-slice 0 ----------------
        {
            int cof = ((lq) ^ sw) * 8;                    // kc=0
            s16x8 af[4], bf4[4];
#pragma unroll
            for (int i = 0; i < 4; i++)
                af[i] = *(const s16x8*)&Ac[(wm + i * 16 + lr) * BK + cof];
#pragma unroll
            for (int i = 0; i < 4; i++)
                bf4[i] = *(const s16x8*)&Bc[(wn + i * 16 + lr) * BK + cof];
            if (st) { stageA(t + 2, bs2, 0); stageA(t + 2, bs2, 1); stageA(t + 2, bs2, 2); }
            __builtin_amdgcn_s_barrier();
            __builtin_amdgcn_s_setprio(1);
#pragma unroll
            for (int tm = 0; tm < 4; tm++)
#pragma unroll
                for (int tn = 0; tn < 4; tn++)
                    acc[tm][tn] = __builtin_amdgcn_mfma_f32_16x16x32_bf16(
                        af[tm], bf4[tn], acc[tm][tn], 0, 0, 0);
            __builtin_amdgcn_s_setprio(0);
        }
        __builtin_amdgcn_s_barrier();

        // ---------------- phase 1: k-slice 1 ----------------
        {
            int cof = ((4 | lq) ^ sw) * 8;                // kc=1
            s16x8 af[4], bf4[4];
#pragma unroll
            for (int i = 0; i < 4; i++)
                af[i] = *(const s16x8*)&Ac[(wm + i * 16 + lr) * BK + cof];
#pragma unroll
            for (int i = 0; i < 4; i++)
                bf4[i] = *(const s16x8*)&Bc[(wn + i * 16 + lr) * BK + cof];
            if (st) { stageA(t + 2, bs2, 3); stageB(t + 2, bs2, 0); stageB(t + 2, bs2, 1); }
            __builtin_amdgcn_s_barrier();
            __builtin_amdgcn_s_setprio(1);
#pragma unroll
            for (int tm = 0; tm < 4; tm++)
#pragma unroll
                for (int tn = 0; tn < 4; tn++)
                    acc[tm][tn] = __builtin_amdgcn_mfma_f32_16x16x32_bf16(
                        af[tm], bf4[tn], acc[tm][tn], 0, 0, 0);
            __builtin_amdgcn_s_setprio(0);
        }

        // ---------------- per-K-tile gate for tile t+1 ----------------
        if (t < NT - 1) {
            if (st) asm volatile("s_waitcnt vmcnt(6)" ::: "memory");
            else    asm volatile("s_waitcnt vmcnt(0)" ::: "memory");
            __builtin_amdgcn_s_barrier();
        }
    }

    // epilogue
#pragma unroll
    for (int tm = 0; tm < 4; tm++) {
#pragma unroll
        for (int tn = 0; tn < 4; tn++) {
#pragma unroll
            for (int r = 0; r < 4; r++) {
                int mrow = bm + wm + tm * 16 + lq * 4 + r;
                int ncol = bn + wn + tn * 16 + lr;
                float vacc = acc[tm][tn][r];
                if (MODE == 1) {
                    vacc = (res[(size_t)mrow * N + ncol] + vacc) * scale;
                } else if (MODE == 2) {
                    vacc = gelu_fast(vacc + bias[ncol]);
                } else if (MODE == 3) {
                    vacc = (res[(size_t)mrow * N + ncol] + vacc + bias[ncol]) * scale;
                }
                if (OBF) ((bf16_t*)Cv)[(size_t)mrow * N + ncol] = f2bf(vacc);
                else     ((float*)Cv)[(size_t)mrow * N + ncol] = vacc;
            }
        }
    }
}

// ---------------------------------------------------------------------------
// Launch
// ---------------------------------------------------------------------------
extern "C" void kernel_launch(void* const* d_in, const int* in_sizes, int n_in,
                              void* d_out, int out_size, void* d_ws, size_t ws_size,
                              hipStream_t stream)
{
    const float* x        = (const float*)d_in[0];
    const float* rel_bias = (const float*)d_in[1];
    const float* wq       = (const float*)d_in[2];
    const float* wk       = (const float*)d_in[3];
    const float* wv       = (const float*)d_in[4];
    const float* w_out    = (const float*)d_in[5];
    const float* ln1_g    = (const float*)d_in[6];
    const float* ln1_b    = (const float*)d_in[7];
    const float* ln2_g    = (const float*)d_in[8];
    const float* ln2_b    = (const float*)d_in[9];
    const float* w1       = (const float*)d_in[10];
    const float* b1       = (const float*)d_in[11];
    const float* w2       = (const float*)d_in[12];
    const float* b2       = (const float*)d_in[13];
    float* out = (float*)d_out;
    float* ws  = (float*)d_ws;

    const size_t SZ = (size_t)ROWS * HID;  // 9,633,792 floats
    // Region map (float units):
    //   [0, SZ/2)    o bf16; y2 bf16 [SZ/2, SZ)
    //   [SZ, 1.5SZ)  q bf16 (dies after attn)   } h bf16 [SZ,3SZ) after attn
    //   [2SZ, 2.5SZ) k bf16 (dies after attn)   }
    //   [3SZ, 3.5SZ) v bf16 (dies after attn)
    //   [4SZ, ...)   bf16 weights: wob 768x768, w1b 3072x768, w2b 768x3072
    bf16_t* q_bf = (bf16_t*)(ws + SZ);
    bf16_t* k_bf = (bf16_t*)(ws + 2 * SZ);
    bf16_t* v_bf = (bf16_t*)(ws + 3 * SZ);
    bf16_t* o_bf = (bf16_t*)ws;
    bf16_t* y2b  = (bf16_t*)(ws + SZ / 2);
    bf16_t* h    = (bf16_t*)(ws + SZ);
    bf16_t* wob  = (bf16_t*)(ws + 4 * SZ);
    bf16_t* w1b  = wob + (size_t)HID * HID;
    bf16_t* w2b  = w1b + (size_t)FFN * HID;

    // 0. weight conversions (one launch)
    cvt_w_kernel<<<(WOUT4 + 2 * W14 + 255) / 256, 256, 0, stream>>>(
        w_out, w1, w2, wob, w1b, w2b);

    // 1+2. fused LN1 + q,k,v per-head projections (MFMA, bf16 out)
    ln_qkv_mfma_kernel<<<ROWS / QKV_T, 256, 0, stream>>>(
        x, ln1_g, ln1_b, wq, wk, wv, q_bf, k_bf, v_bf);

    // 3. o = softmax((qk^T + bias)/sqrt(d)) @ v   (MFMA, bf16 out) [13-tile]
    attn_mfma_kernel<<<dim3(NHEAD, NB), 256, 0, stream>>>(q_bf, k_bf, v_bf, rel_bias, o_bf);

    // 4. x1 = (x + o @ w_out^T) * RATE   -> d_out (fp32)   [r2 dbuf TM=64]
    gemm_mfma<1, false, 64><<<(ROWS / 64) * (HID / 128), 256, 0, stream>>>(
        o_bf, wob, out, ROWS, HID, HID, nullptr, x, RATE);

    // 5. y2 = LN2(x1)  (bf16)   [wave-per-row, shuffle-only: 3136 blks]
    ln_wave_kernel<<<ROWS / 4, 256, 0, stream>>>(out, ln2_g, ln2_b, y2b);

    // 6. h = gelu(y2 @ w1^T + b1)  (bf16)   [r4 fph: 1176 blks]
    gemm_fph<2, true><<<(ROWS / 256) * (FFN / 128), 512, 0, stream>>>(
        y2b, w1b, h, ROWS, FFN, HID, b1, nullptr, 1.0f);

    // 7. out = (x1 + h @ w2^T + b2) * RATE  (fp32)   [r2 dbuf TM=64]
    gemm_mfma<3, false, 64><<<(ROWS / 64) * (HID / 128), 256, 0, stream>>>(
        h, w2b, out, ROWS, HID, FFN, b2, out, RATE);
}